// Round 8
// baseline (689.541 us; speedup 1.0000x reference)
//
#include <hip/hip_runtime.h>
#include <hip/hip_bf16.h>

// Problem constants
#define B_ 4
#define S_ 2048
#define E_ 2048
#define H_ 16
#define D_ 128
#define M_ (B_*S_)   // 8192 rows

typedef __attribute__((ext_vector_type(8))) short short8;
typedef __attribute__((ext_vector_type(4))) float f32x4;

__device__ __forceinline__ unsigned short f2bf(float f) {
  union { __hip_bfloat16 h; unsigned short u; } c;
  c.h = __float2bfloat16(f);
  return c.u;
}

__device__ __forceinline__ void gld_lds16(const void* g, void* l) {
  __builtin_amdgcn_global_load_lds((const __attribute__((address_space(1))) void*)g,
                                   (__attribute__((address_space(3))) void*)l, 16, 0, 0);
}

// ---------------- fp32 -> bf16 cast (vectorized) ----------------
__global__ __launch_bounds__(256) void cast_bf16_kernel(const float* __restrict__ in,
                                                        unsigned short* __restrict__ out,
                                                        int n4) {
  int i = blockIdx.x * 256 + threadIdx.x;
  if (i >= n4) return;
  float4 v = ((const float4*)in)[i];
  ushort4 o;
  o.x = f2bf(v.x); o.y = f2bf(v.y); o.z = f2bf(v.z); o.w = f2bf(v.w);
  ((ushort4*)out)[i] = o;
}

// ---------------- GEMM: C[M,N] = (A[M,K] @ W[N,K]^T + bias) * oscale ----------------
// m97 structure: 128x128 tile, BK=32, 4 waves (2x2 of 64x64), global_load_lds w16.
// TR=true: store C^T (C_T[N][M]) via swapped-operand MFMA (A-frag of X == B-frag
// of X^T, same lane regs): acc = mfma(bf, af) -> D[n][m], n = lg*4+r, m = lr.
template <typename OutT, bool TR = false>
__global__ __launch_bounds__(256) void gemm_bt(const unsigned short* __restrict__ A,
                                               const unsigned short* __restrict__ W,
                                               const float* __restrict__ bias,
                                               OutT* __restrict__ C,
                                               int M, int N, int K, float oscale) {
  __shared__ unsigned short As[128 * 32];
  __shared__ unsigned short Bs[128 * 32];
  const int tid  = threadIdx.x;
  const int lane = tid & 63;
  const int wid  = tid >> 6;
  const int m0 = blockIdx.y * 128;
  const int n0 = blockIdx.x * 128;
  const int wr = (wid >> 1) * 64;   // wave row offset in tile
  const int wc = (wid & 1) * 64;    // wave col offset in tile
  const int lr  = lane & 15;
  const int lk8 = (lane >> 4) * 8;

  f32x4 acc[4][4];
#pragma unroll
  for (int i = 0; i < 4; i++)
#pragma unroll
    for (int j = 0; j < 4; j++) acc[i][j] = (f32x4){0.f, 0.f, 0.f, 0.f};

  // staging: tile is 128 rows x 32 cols bf16 = 8192 B; 256 thr x 16 B = 4096 B/pass
  const int o0 = tid * 16;            // byte offset in tile, pass 0
  const int row0 = o0 >> 6, colb0 = o0 & 63;
  const int o1 = o0 + 4096;           // pass 1
  const int row1 = o1 >> 6, colb1 = o1 & 63;
  const int ldsb0 = wid * 1024;       // wave-uniform LDS byte base, pass 0
  const int ldsb1 = wid * 1024 + 4096;

  for (int kt = 0; kt < K; kt += 32) {
    gld_lds16(A + (size_t)(m0 + row0) * K + kt + (colb0 >> 1), (char*)As + ldsb0);
    gld_lds16(A + (size_t)(m0 + row1) * K + kt + (colb1 >> 1), (char*)As + ldsb1);
    gld_lds16(W + (size_t)(n0 + row0) * K + kt + (colb0 >> 1), (char*)Bs + ldsb0);
    gld_lds16(W + (size_t)(n0 + row1) * K + kt + (colb1 >> 1), (char*)Bs + ldsb1);
    __syncthreads();

    short8 af[4], bf[4];
#pragma unroll
    for (int i = 0; i < 4; i++) af[i] = *(const short8*)&As[(wr + i * 16 + lr) * 32 + lk8];
#pragma unroll
    for (int j = 0; j < 4; j++) bf[j] = *(const short8*)&Bs[(wc + j * 16 + lr) * 32 + lk8];
#pragma unroll
    for (int i = 0; i < 4; i++)
#pragma unroll
      for (int j = 0; j < 4; j++) {
        if constexpr (TR)
          acc[i][j] = __builtin_amdgcn_mfma_f32_16x16x32_bf16(bf[j], af[i], acc[i][j], 0, 0, 0);
        else
          acc[i][j] = __builtin_amdgcn_mfma_f32_16x16x32_bf16(af[i], bf[j], acc[i][j], 0, 0, 0);
      }
    __syncthreads();
  }

  if constexpr (TR) {
    // C^T epilogue: D[n][m], n = wc+j*16+lg*4+r, m = wr+i*16+lr  [swapped m89]
    const int lg4 = (lane >> 4) * 4;
#pragma unroll
    for (int j = 0; j < 4; j++) {
      const int gn = n0 + wc + j * 16 + lg4;
      const float4 bv4 = *(const float4*)&bias[gn];
#pragma unroll
      for (int i = 0; i < 4; i++) {
        const int gm = m0 + wr + i * 16 + lr;
#pragma unroll
        for (int r = 0; r < 4; r++) {
          const float v = (acc[i][j][r] + ((const float*)&bv4)[r]) * oscale;
          ((unsigned short*)C)[(size_t)(gn + r) * M + gm] = f2bf(v);
        }
      }
    }
  } else {
    // epilogue: C/D layout col=lane&15, row=(lane>>4)*4+r  [m89-verified]
#pragma unroll
    for (int i = 0; i < 4; i++) {
      const int gm = m0 + wr + i * 16 + (lane >> 4) * 4;
#pragma unroll
      for (int j = 0; j < 4; j++) {
        const int gn = n0 + wc + j * 16 + lr;
        const float bv = bias[gn];
#pragma unroll
        for (int r = 0; r < 4; r++) {
          const float v = (acc[i][j][r] + bv) * oscale;
          if constexpr (sizeof(OutT) == 2)
            ((unsigned short*)C)[(size_t)(gm + r) * N + gn] = f2bf(v);
          else
            ((float*)C)[(size_t)(gm + r) * N + gn] = v;
        }
      }
    }
  }
}

// ---------------- causal flash attention (folded, swapped ops, dbuf pipeline) ----------------
// r7-verified structure: 4 waves/block, wave owns 16 q rows, block handles
// q-tiles bx and 31-bx (66 steps, balanced). Q pre-scaled by 1/sqrt(D) in the
// Q-GEMM epilogue, so scores are used raw here.
//
// NEW vs r7: K/V tiles DOUBLE-BUFFERED, ONE barrier per step:
//   prologue: STAGE(0 -> buf0)
//   iter t:   __syncthreads()            // vmcnt(0) drain -> buf[t&1] staged;
//                                        // all waves' reads of buf^1 finished
//             STAGE(t+1 -> buf^1)        // lands during compute(t)
//             compute(t) from buf[t&1]
// Staging latency hides under a full compute phase instead of being exposed
// at a same-step barrier (the r7 bottleneck). LDS 36 KB; grid 1024 = 4
// blocks/CU (grid-limited), so dbuf costs no occupancy (unlike r3).
// T5: s_setprio(1) around both MFMA clusters.
__global__ __launch_bounds__(256) void flash_attn(const unsigned short* __restrict__ Q,
                                                  const unsigned short* __restrict__ K,
                                                  const unsigned short* __restrict__ VT,
                                                  unsigned short* __restrict__ Ctx) {
  __shared__ unsigned short Ks[2 * 32 * 128];   // 16 KB, swizzled K tiles
  __shared__ unsigned short Vt[2 * 128 * 32];   // 16 KB, swizzled V^T tiles
  __shared__ unsigned short Pl[4 * 512];        // 4 KB, per-wave P feed tiles

  const int tid  = threadIdx.x;
  const int lane = tid & 63;
  const int wid  = tid >> 6;
  const int lr  = lane & 15;
  const int lg  = lane >> 4;
  const int lk8 = lg * 8;
  const int h  = blockIdx.y;
  const int b  = blockIdx.z;
  const size_t base = ((size_t)b * S_) * E_ + (size_t)h * D_;
  const unsigned short* __restrict__ Kh = K + base;
  // VT head base: row h*D+d, col b*S+kv
  const unsigned short* __restrict__ VTh = VT + (size_t)(h * D_) * M_ + (size_t)b * S_;
  unsigned short* Plf = Pl + wid * 512;

  // ---- K staging geometry (per 32x128 tile = 8192 B; 2 passes x 4096 B) ----
  const int oK0 = tid * 16;
  const int rK0 = oK0 >> 8;                 // rows 0..15
  const int cK0 = (oK0 & 255) ^ ((rK0 & 7) << 4);
  const int rK1 = (oK0 + 4096) >> 8;        // rows 16..31
  const int cK1 = (oK0 & 255) ^ ((rK1 & 7) << 4);
  const unsigned short* ksrc0 = Kh + (size_t)rK0 * E_ + (cK0 >> 1);
  const unsigned short* ksrc1 = Kh + (size_t)rK1 * E_ + (cK1 >> 1);
  char* kdst0 = (char*)Ks + wid * 1024;            // + buf*8192
  char* kdst1 = (char*)Ks + 4096 + wid * 1024;

  // ---- V^T staging geometry (r7-verified): d = pass*64 + tid>>2, chunk tid&3;
  // LDS dest linear (tid*16), global source chunk pre-swizzled (rule 21) ----
  const int dV0 = tid >> 2;                 // 0..63
  const int dV1 = 64 + dV0;                 // 64..127
  const int cV  = tid & 3;
  const int swV0 = ((dV0 >> 1) & 3) ^ ((dV0 >> 4) & 3);
  const int swV1 = ((dV1 >> 1) & 3) ^ ((dV1 >> 4) & 3);
  const unsigned short* vsrc0 = VTh + (size_t)dV0 * M_ + (cV ^ swV0) * 8;
  const unsigned short* vsrc1 = VTh + (size_t)dV1 * M_ + (cV ^ swV1) * 8;
  char* vdst0 = (char*)Vt + wid * 1024;            // + buf*8192
  char* vdst1 = (char*)Vt + 4096 + wid * 1024;

  // ---- P feed addresses (per-lane, constant across steps) ----
  const int plw0 = (lg >> 1) * 128 + lr * 8 + (lg & 1) * 4;  // p0 pack (4 u16)
  const int plrd = lg * 128 + lr * 8;                         // B-frag read (16B)

#pragma unroll 1
  for (int half = 0; half < 2; ++half) {
    const int ti = half ? (31 - (int)blockIdx.x) : (int)blockIdx.x;
    const int qblk = ti * 64;               // q-tile base
    const int q0w  = qblk + wid * 16;       // this wave's q rows
    const int qrow = q0w + lr;              // this lane's softmax row

    // ---- Q fragments (pre-scaled by 1/sqrt(D) in Q-GEMM) ----
    short8 qf[4];
#pragma unroll
    for (int kk = 0; kk < 4; kk++)
      qf[kk] = *(const short8*)&Q[base + (size_t)(q0w + lr) * E_ + kk * 32 + lk8];

    f32x4 o[8];
#pragma unroll
    for (int d0 = 0; d0 < 8; d0++) o[d0] = (f32x4){0.f, 0.f, 0.f, 0.f};
    float mrow = -INFINITY;
    float lsum = 0.f;

    const int nt = (qblk >> 5) + 2;         // (qblk+64)/32 kv steps

    // ---- prologue: stage tile 0 into buf 0 ----
    gld_lds16(ksrc0, kdst0);
    gld_lds16(ksrc1, kdst1);
    gld_lds16(vsrc0, vdst0);
    gld_lds16(vsrc1, vdst1);

    for (int t = 0; t < nt; ++t) {
      const int buf = t & 1;
      const int bo  = buf * 8192;           // byte offset of current buffer
      __syncthreads();   // vmcnt(0) drain: buf staged; buf^1 reads all done

      // ---- issue next-tile staging into buf^1 (lands during compute) ----
      if (t + 1 < nt) {
        const size_t koff = (size_t)(t + 1) * 32 * E_;
        const int nbo = bo ^ 8192;
        gld_lds16(ksrc0 + koff, kdst0 + nbo);
        gld_lds16(ksrc1 + koff, kdst1 + nbo);
        gld_lds16(vsrc0 + (t + 1) * 32, vdst0 + nbo);
        gld_lds16(vsrc1 + (t + 1) * 32, vdst1 + nbo);
      }

      const int kv0 = t * 32;
      if (kv0 < q0w + 16) {    // wave has unmasked kv cols this step
        // ---- S^T = K Q^T : lane holds S[kv0 + lg*4+r (+16)][qrow] ----
        f32x4 s0 = (f32x4){0.f, 0.f, 0.f, 0.f};
        f32x4 s1 = (f32x4){0.f, 0.f, 0.f, 0.f};
        const int swK = (lr & 7) << 4;
        const char* KsB = (const char*)Ks + bo;
        __builtin_amdgcn_s_setprio(1);
#pragma unroll
        for (int kk = 0; kk < 4; kk++) {
          const int cb = (kk * 64 + lg * 16) ^ swK;
          short8 k0 = *(const short8*)(KsB + lr * 256 + cb);
          short8 k1 = *(const short8*)(KsB + (16 + lr) * 256 + cb);
          s0 = __builtin_amdgcn_mfma_f32_16x16x32_bf16(k0, qf[kk], s0, 0, 0, 0);
          s1 = __builtin_amdgcn_mfma_f32_16x16x32_bf16(k1, qf[kk], s1, 0, 0, 0);
        }
        __builtin_amdgcn_s_setprio(0);

        // ---- masked scores (already scaled); in-lane reduce + 2 shuffles ----
        const int kvb0 = kv0 + lg * 4;       // s0 kv base
        float v0[4], v1[4];
#pragma unroll
        for (int r = 0; r < 4; r++) {
          v0[r] = (kvb0 + r      <= qrow) ? s0[r] : -INFINITY;
          v1[r] = (kvb0 + 16 + r <= qrow) ? s1[r] : -INFINITY;
        }
        float pm = fmaxf(fmaxf(fmaxf(v0[0], v0[1]), fmaxf(v0[2], v0[3])),
                         fmaxf(fmaxf(v1[0], v1[1]), fmaxf(v1[2], v1[3])));
        pm = fmaxf(pm, __shfl_xor(pm, 16));
        pm = fmaxf(pm, __shfl_xor(pm, 32));

        // ---- online softmax with defer-max (T13, THR=8) ----
        float p0[4], p1[4];
        const float need = pm - mrow;        // first iter: +inf -> slow path
        if (__all(need <= 8.f)) {
          // fast path: keep old max, skip alpha/rescale (P bounded by e^8)
#pragma unroll
          for (int r = 0; r < 4; r++) {
            p0[r] = __expf(v0[r] - mrow);
            p1[r] = __expf(v1[r] - mrow);
          }
          float ps = (p0[0] + p0[1]) + (p0[2] + p0[3])
                   + (p1[0] + p1[1]) + (p1[2] + p1[3]);
          ps += __shfl_xor(ps, 16);
          ps += __shfl_xor(ps, 32);
          lsum += ps;
        } else {
          const float mnew = fmaxf(mrow, pm);
          const float al = __expf(mrow - mnew);   // first iter: exp(-inf)=0
#pragma unroll
          for (int r = 0; r < 4; r++) {
            p0[r] = __expf(v0[r] - mnew);
            p1[r] = __expf(v1[r] - mnew);
          }
          mrow = mnew;
          float ps = (p0[0] + p0[1]) + (p0[2] + p0[3])
                   + (p1[0] + p1[1]) + (p1[2] + p1[3]);
          ps += __shfl_xor(ps, 16);
          ps += __shfl_xor(ps, 32);
          lsum = lsum * al + ps;
#pragma unroll
          for (int d0 = 0; d0 < 8; ++d0) {
            f32x4 tt = o[d0];
            tt[0] *= al; tt[1] *= al; tt[2] *= al; tt[3] *= al;
            o[d0] = tt;
          }
        }

        // ---- P -> per-wave feed tile (two packed 8B writes) ----
        ushort4 w0, w1;
        w0.x = f2bf(p0[0]); w0.y = f2bf(p0[1]); w0.z = f2bf(p0[2]); w0.w = f2bf(p0[3]);
        w1.x = f2bf(p1[0]); w1.y = f2bf(p1[1]); w1.z = f2bf(p1[2]); w1.w = f2bf(p1[3]);
        *(ushort4*)&Plf[plw0]       = w0;
        *(ushort4*)&Plf[plw0 + 256] = w1;
        // wave-local data only: drain Plf writes; fence scheduler (rule 18)
        asm volatile("s_waitcnt lgkmcnt(0)" ::: "memory");
        __builtin_amdgcn_sched_barrier(0);

        // ---- O^T += V^T P : vb = A-frag of V^T (r5/r7-verbatim read) ----
        const short8 pb = *(const short8*)&Plf[plrd];
        const unsigned short* VtB = Vt + (bo >> 1);
        __builtin_amdgcn_s_setprio(1);
#pragma unroll
        for (int d0 = 0; d0 < 8; ++d0) {
          const int d = d0 * 16 + lr;
          const int sw = ((d >> 1) & 3) ^ ((d >> 4) & 3);
          const short8 vb = *(const short8*)&VtB[d * 32 + ((lg ^ sw) << 3)];
          o[d0] = __builtin_amdgcn_mfma_f32_16x16x32_bf16(vb, pb, o[d0], 0, 0, 0);
        }
        __builtin_amdgcn_s_setprio(0);
      }
    }
    __syncthreads();   // protect buffers before next half's prologue

    // ---- normalize + store ctx (bf16): o[d0][r] = O[qrow][d0*16+lg*4+r] ----
    const float inv = 1.0f / lsum;
    unsigned short* crow = Ctx + base + (size_t)qrow * E_ + lg * 4;
#pragma unroll
    for (int d0 = 0; d0 < 8; ++d0) {
      ushort4 st;
      st.x = f2bf(o[d0][0] * inv);
      st.y = f2bf(o[d0][1] * inv);
      st.z = f2bf(o[d0][2] * inv);
      st.w = f2bf(o[d0][3] * inv);
      *(ushort4*)&crow[d0 * 16] = st;
    }
  }
}

// ---------------- launcher ----------------
extern "C" void kernel_launch(void* const* d_in, const int* in_sizes, int n_in,
                              void* d_out, int out_size, void* d_ws, size_t ws_size,
                              hipStream_t stream) {
  const float* x  = (const float*)d_in[0];
  // d_in[1] = causal_mask (tril) — implemented analytically
  const float* wq = (const float*)d_in[2];
  const float* bq = (const float*)d_in[3];
  const float* wk = (const float*)d_in[4];
  const float* bk = (const float*)d_in[5];
  const float* wv = (const float*)d_in[6];
  const float* bv = (const float*)d_in[7];
  const float* wo = (const float*)d_in[8];
  const float* bo = (const float*)d_in[9];
  float* out = (float*)d_out;

  char* ws = (char*)d_ws;
  const size_t MB = 1024 * 1024;
  unsigned short* xb  = (unsigned short*)(ws);             // 32 MB
  unsigned short* wqb = (unsigned short*)(ws + 32 * MB);   // 8 MB
  unsigned short* wkb = (unsigned short*)(ws + 40 * MB);   // 8 MB
  unsigned short* wvb = (unsigned short*)(ws + 48 * MB);   // 8 MB
  unsigned short* wob = (unsigned short*)(ws + 56 * MB);   // 8 MB
  unsigned short* Qb  = (unsigned short*)(ws + 64 * MB);   // 32 MB
  unsigned short* Kb  = (unsigned short*)(ws + 96 * MB);   // 32 MB
  unsigned short* VTb = (unsigned short*)(ws + 128 * MB);  // 32 MB, V^T [E][M]
  unsigned short* Cb  = (unsigned short*)(ws + 160 * MB);  // 32 MB -> 192 MB total

  const int nx4 = M_ * E_ / 4;   // x elements /4
  const int nw4 = E_ * E_ / 4;   // weight elements /4
  cast_bf16_kernel<<<nx4 / 256, 256, 0, stream>>>(x,  xb,  nx4);
  cast_bf16_kernel<<<nw4 / 256, 256, 0, stream>>>(wq, wqb, nw4);
  cast_bf16_kernel<<<nw4 / 256, 256, 0, stream>>>(wk, wkb, nw4);
  cast_bf16_kernel<<<nw4 / 256, 256, 0, stream>>>(wv, wvb, nw4);
  cast_bf16_kernel<<<nw4 / 256, 256, 0, stream>>>(wo, wob, nw4);

  const float scale = 0.08838834764831845f;  // 1/sqrt(128), folded into Q
  dim3 gg(E_ / 128, M_ / 128);   // (16, 64)
  gemm_bt<unsigned short><<<gg, 256, 0, stream>>>(xb, wqb, bq, Qb, M_, E_, E_, scale);
  gemm_bt<unsigned short><<<gg, 256, 0, stream>>>(xb, wkb, bk, Kb, M_, E_, E_, 1.0f);
  // V-projection writes V^T [E][M] directly (swapped-operand TR epilogue)
  gemm_bt<unsigned short, true><<<gg, 256, 0, stream>>>(xb, wvb, bv, VTb, M_, E_, E_, 1.0f);

  // folded causal grid: block bx handles q-tiles bx and 31-bx (66 steps each)
  flash_attn<<<dim3(S_ / 64 / 2, H_, B_), 256, 0, stream>>>(Qb, Kb, VTb, Cb);

  gemm_bt<float><<<gg, 256, 0, stream>>>(Cb, wob, bo, out, M_, E_, E_, 1.0f);
}

// Round 9
// 650.107 us; speedup vs baseline: 1.0607x; 1.0607x over previous
//
#include <hip/hip_runtime.h>
#include <hip/hip_bf16.h>

// Problem constants
#define B_ 4
#define S_ 2048
#define E_ 2048
#define H_ 16
#define D_ 128
#define M_ (B_*S_)   // 8192 rows

typedef __attribute__((ext_vector_type(8))) short short8;
typedef __attribute__((ext_vector_type(4))) float f32x4;

__device__ __forceinline__ unsigned short f2bf(float f) {
  union { __hip_bfloat16 h; unsigned short u; } c;
  c.h = __float2bfloat16(f);
  return c.u;
}

__device__ __forceinline__ void gld_lds16(const void* g, void* l) {
  __builtin_amdgcn_global_load_lds((const __attribute__((address_space(1))) void*)g,
                                   (__attribute__((address_space(3))) void*)l, 16, 0, 0);
}

// ---------------- fp32 -> bf16 cast (vectorized) ----------------
__global__ __launch_bounds__(256) void cast_bf16_kernel(const float* __restrict__ in,
                                                        unsigned short* __restrict__ out,
                                                        int n4) {
  int i = blockIdx.x * 256 + threadIdx.x;
  if (i >= n4) return;
  float4 v = ((const float4*)in)[i];
  ushort4 o;
  o.x = f2bf(v.x); o.y = f2bf(v.y); o.z = f2bf(v.z); o.w = f2bf(v.w);
  ((ushort4*)out)[i] = o;
}

// ---------------- GEMM: C[M,N] = (A[M,K] @ W[N,K]^T + bias) * oscale ----------------
// m97 structure: 128x128 tile, BK=32, 4 waves (2x2 of 64x64), global_load_lds w16.
// TR=true: store C^T (C_T[N][M]) via swapped-operand MFMA (A-frag of X == B-frag
// of X^T, same lane regs): acc = mfma(bf, af) -> D[n][m], n = lg*4+r, m = lr.
template <typename OutT, bool TR = false>
__global__ __launch_bounds__(256) void gemm_bt(const unsigned short* __restrict__ A,
                                               const unsigned short* __restrict__ W,
                                               const float* __restrict__ bias,
                                               OutT* __restrict__ C,
                                               int M, int N, int K, float oscale) {
  __shared__ unsigned short As[128 * 32];
  __shared__ unsigned short Bs[128 * 32];
  const int tid  = threadIdx.x;
  const int lane = tid & 63;
  const int wid  = tid >> 6;
  const int m0 = blockIdx.y * 128;
  const int n0 = blockIdx.x * 128;
  const int wr = (wid >> 1) * 64;   // wave row offset in tile
  const int wc = (wid & 1) * 64;    // wave col offset in tile
  const int lr  = lane & 15;
  const int lk8 = (lane >> 4) * 8;

  f32x4 acc[4][4];
#pragma unroll
  for (int i = 0; i < 4; i++)
#pragma unroll
    for (int j = 0; j < 4; j++) acc[i][j] = (f32x4){0.f, 0.f, 0.f, 0.f};

  // staging: tile is 128 rows x 32 cols bf16 = 8192 B; 256 thr x 16 B = 4096 B/pass
  const int o0 = tid * 16;            // byte offset in tile, pass 0
  const int row0 = o0 >> 6, colb0 = o0 & 63;
  const int o1 = o0 + 4096;           // pass 1
  const int row1 = o1 >> 6, colb1 = o1 & 63;
  const int ldsb0 = wid * 1024;       // wave-uniform LDS byte base, pass 0
  const int ldsb1 = wid * 1024 + 4096;

  for (int kt = 0; kt < K; kt += 32) {
    gld_lds16(A + (size_t)(m0 + row0) * K + kt + (colb0 >> 1), (char*)As + ldsb0);
    gld_lds16(A + (size_t)(m0 + row1) * K + kt + (colb1 >> 1), (char*)As + ldsb1);
    gld_lds16(W + (size_t)(n0 + row0) * K + kt + (colb0 >> 1), (char*)Bs + ldsb0);
    gld_lds16(W + (size_t)(n0 + row1) * K + kt + (colb1 >> 1), (char*)Bs + ldsb1);
    __syncthreads();

    short8 af[4], bf[4];
#pragma unroll
    for (int i = 0; i < 4; i++) af[i] = *(const short8*)&As[(wr + i * 16 + lr) * 32 + lk8];
#pragma unroll
    for (int j = 0; j < 4; j++) bf[j] = *(const short8*)&Bs[(wc + j * 16 + lr) * 32 + lk8];
#pragma unroll
    for (int i = 0; i < 4; i++)
#pragma unroll
      for (int j = 0; j < 4; j++) {
        if constexpr (TR)
          acc[i][j] = __builtin_amdgcn_mfma_f32_16x16x32_bf16(bf[j], af[i], acc[i][j], 0, 0, 0);
        else
          acc[i][j] = __builtin_amdgcn_mfma_f32_16x16x32_bf16(af[i], bf[j], acc[i][j], 0, 0, 0);
      }
    __syncthreads();
  }

  if constexpr (TR) {
    // C^T epilogue: D[n][m], n = wc+j*16+lg*4+r, m = wr+i*16+lr  [swapped m89]
    const int lg4 = (lane >> 4) * 4;
#pragma unroll
    for (int j = 0; j < 4; j++) {
      const int gn = n0 + wc + j * 16 + lg4;
      const float4 bv4 = *(const float4*)&bias[gn];
#pragma unroll
      for (int i = 0; i < 4; i++) {
        const int gm = m0 + wr + i * 16 + lr;
#pragma unroll
        for (int r = 0; r < 4; r++) {
          const float v = (acc[i][j][r] + ((const float*)&bv4)[r]) * oscale;
          ((unsigned short*)C)[(size_t)(gn + r) * M + gm] = f2bf(v);
        }
      }
    }
  } else {
    // epilogue: C/D layout col=lane&15, row=(lane>>4)*4+r  [m89-verified]
#pragma unroll
    for (int i = 0; i < 4; i++) {
      const int gm = m0 + wr + i * 16 + (lane >> 4) * 4;
#pragma unroll
      for (int j = 0; j < 4; j++) {
        const int gn = n0 + wc + j * 16 + lr;
        const float bv = bias[gn];
#pragma unroll
        for (int r = 0; r < 4; r++) {
          const float v = (acc[i][j][r] + bv) * oscale;
          if constexpr (sizeof(OutT) == 2)
            ((unsigned short*)C)[(size_t)(gm + r) * N + gn] = f2bf(v);
          else
            ((float*)C)[(size_t)(gm + r) * N + gn] = v;
        }
      }
    }
  }
}

// ---------------- causal flash attention (folded, swapped ops, KVBLK=64) ----------------
// 4 waves/block, wave owns 16 q rows (64-row q-tile); block handles q-tiles
// bx and 31-bx -> 33 steps of 64 kv each, perfectly balanced. Single-buffered
// (r8 post-mortem: dbuf neutral-to-negative; TLP hides staging latency).
// Q pre-scaled by 1/sqrt(D) in the Q-GEMM epilogue.
//
// KVBLK=64: one step covers 64 kv -> barriers, loop overhead, max-tree and
// Pl round-trip amortize 2x vs r7. Causal masking runs ONLY on the diagonal
// step (t == nt-1): all earlier steps satisfy kv0+63 < q0w for every wave.
// lsum kept as per-lane partial (rescale by row-uniform alpha is exact);
// reduced once per tile.
//
// Layouts (r7-verified, row extension preserves swizzle invariants):
//   Ks[64][128] bf16: XOR-swizzle cb ^= (row&7)<<4 via pre-swizzled gld_lds
//     source (linear LDS dest, rule 21). row&7 == lr&7 on reads.
//   Vt[128][64] bf16 (V^T): per-row 8 chunks of 16B, chunk c at c ^ (d&7),
//     pre-swizzled on the gld_lds source; reads 2-way bank aliased (free).
//   Plf per wave [64][16] feed: write 4x ushort4 at plw0 + c*256, read
//     short8 at plrd + kk*512 (B-frag of P).
//   S^T = mfma(kf, qf): lane holds S[kv0 + c*16 + lg*4 + r][qrow = q0w+lr].
//   O^T = mfma(vb, pb): o[d0][r] = O[qrow][d0*16 + lg*4 + r].
__global__ __launch_bounds__(256, 4) void flash_attn(const unsigned short* __restrict__ Q,
                                                     const unsigned short* __restrict__ K,
                                                     const unsigned short* __restrict__ VT,
                                                     unsigned short* __restrict__ Ctx) {
  __shared__ unsigned short Ks[64 * 128];    // 16 KB, swizzled K tile
  __shared__ unsigned short Vt[128 * 64];    // 16 KB, swizzled V^T tile
  __shared__ unsigned short Pl[4 * 1024];    // 8 KB, per-wave P feed tiles

  const int tid  = threadIdx.x;
  const int lane = tid & 63;
  const int wid  = tid >> 6;
  const int lr  = lane & 15;
  const int lg  = lane >> 4;
  const int lk8 = lg * 8;
  const int h  = blockIdx.y;
  const int b  = blockIdx.z;
  const size_t base = ((size_t)b * S_) * E_ + (size_t)h * D_;
  const unsigned short* __restrict__ Kh = K + base;
  // VT head base: row h*D+d, col b*S+kv
  const unsigned short* __restrict__ VTh = VT + (size_t)(h * D_) * M_ + (size_t)b * S_;
  unsigned short* Plf = Pl + wid * 1024;

  // ---- K staging geometry: tile 64x128 = 16 KB; 4 passes x 4096 B ----
  // pass p: row = (tid>>4) + 16p, colbyte = ((tid*16)&255) ^ ((row&7)<<4)
  // (row&7 invariant across passes since 16 == 0 mod 8... 16p mod 8 == 0)
  const int rK = tid >> 4;                  // 0..15
  const int cK = ((tid * 16) & 255) ^ ((rK & 7) << 4);
  const unsigned short* ksrcB = Kh + (size_t)rK * E_ + (cK >> 1);
  char* kdstB = (char*)Ks + wid * 1024;     // + p*4096

  // ---- V^T staging geometry: tile 128 d x 128 B = 16 KB; 4 passes ----
  // pass p: d = (tid>>3) + 32p, chunk = tid&7; source chunk pre-swizzled
  const int dVb = tid >> 3;                 // 0..31
  const int cV  = tid & 7;
  const unsigned short* vsrcB = VTh + (size_t)dVb * M_ + (size_t)((cV ^ (dVb & 7)) * 8);
  char* vdstB = (char*)Vt + wid * 1024;     // + p*4096

  // ---- P feed addresses (per-lane, constant across steps) ----
  const int plw0 = (lg >> 1) * 128 + lr * 8 + (lg & 1) * 4;  // pack c at +c*256
  const int plrd = lg * 128 + lr * 8;                         // B-frag kk at +kk*512

#pragma unroll 1
  for (int half = 0; half < 2; ++half) {
    const int ti = half ? (31 - (int)blockIdx.x) : (int)blockIdx.x;
    const int qblk = ti * 64;               // q-tile base
    const int q0w  = qblk + wid * 16;       // this wave's q rows
    const int qrow = q0w + lr;              // this lane's softmax row

    // ---- Q fragments (pre-scaled by 1/sqrt(D) in Q-GEMM) ----
    short8 qf[4];
#pragma unroll
    for (int kk = 0; kk < 4; kk++)
      qf[kk] = *(const short8*)&Q[base + (size_t)qrow * E_ + kk * 32 + lk8];

    f32x4 o[8];
#pragma unroll
    for (int d0 = 0; d0 < 8; d0++) o[d0] = (f32x4){0.f, 0.f, 0.f, 0.f};
    float mrow = -INFINITY;
    float lsum = 0.f;                       // per-lane partial (lazy reduce)

    const int nt = ti + 1;                  // steps of 64 kv

    for (int t = 0; t < nt; ++t) {
      const int kv0 = t * 64;
      const size_t koff = (size_t)kv0 * E_;

      // ---- stage K + V^T (8 async global_load_lds; zero staging VALU) ----
#pragma unroll
      for (int p = 0; p < 4; ++p) {
        gld_lds16(ksrcB + koff + (size_t)(16 * p) * E_, kdstB + p * 4096);
        gld_lds16(vsrcB + (size_t)(32 * p) * M_ + kv0,  vdstB + p * 4096);
      }
      __syncthreads();   // barrier drain: tile staged

      // ---- S^T = K Q^T : quadrant c holds S[kv0+c*16+lg*4+r][qrow] ----
      f32x4 s[4];
#pragma unroll
      for (int c = 0; c < 4; c++) s[c] = (f32x4){0.f, 0.f, 0.f, 0.f};
      const int swK = (lr & 7) << 4;
      __builtin_amdgcn_s_setprio(1);
#pragma unroll
      for (int kk = 0; kk < 4; kk++) {
        const int cb = (kk * 64 + lg * 16) ^ swK;
#pragma unroll
        for (int c = 0; c < 4; c++) {
          const short8 kf = *(const short8*)((const char*)Ks + (c * 16 + lr) * 256 + cb);
          s[c] = __builtin_amdgcn_mfma_f32_16x16x32_bf16(kf, qf[kk], s[c], 0, 0, 0);
        }
      }
      __builtin_amdgcn_s_setprio(0);

      // ---- scores (pre-scaled); mask only on the diagonal step ----
      float v[4][4];
#pragma unroll
      for (int c = 0; c < 4; c++)
#pragma unroll
        for (int r = 0; r < 4; r++) v[c][r] = s[c][r];
      if (t == nt - 1) {   // uniform branch: diagonal 64-block
#pragma unroll
        for (int c = 0; c < 4; c++) {
          const int kvq = kv0 + c * 16 + lg * 4;
#pragma unroll
          for (int r = 0; r < 4; r++)
            if (kvq + r > qrow) v[c][r] = -INFINITY;
        }
      }

      // ---- row max: 15 in-lane fmax + 2 shuffles ----
      float pm = fmaxf(fmaxf(fmaxf(v[0][0], v[0][1]), fmaxf(v[0][2], v[0][3])),
                       fmaxf(fmaxf(v[1][0], v[1][1]), fmaxf(v[1][2], v[1][3])));
      pm = fmaxf(pm, fmaxf(fmaxf(fmaxf(v[2][0], v[2][1]), fmaxf(v[2][2], v[2][3])),
                           fmaxf(fmaxf(v[3][0], v[3][1]), fmaxf(v[3][2], v[3][3]))));
      pm = fmaxf(pm, __shfl_xor(pm, 16));
      pm = fmaxf(pm, __shfl_xor(pm, 32));

      // ---- defer-max (T13, THR=8): rescale only when max grows a lot ----
      const float need = pm - mrow;          // first step: +inf -> slow path
      if (!__all(need <= 8.f)) {
        const float mnew = fmaxf(mrow, pm);
        const float al = __expf(mrow - mnew);   // first step: exp(-inf)=0
        lsum *= al;
#pragma unroll
        for (int d0 = 0; d0 < 8; ++d0) {
          f32x4 tt = o[d0];
          tt[0] *= al; tt[1] *= al; tt[2] *= al; tt[3] *= al;
          o[d0] = tt;
        }
        mrow = mnew;
      }

      // ---- exp + pack + per-lane partial sum (no per-step shuffles) ----
      ushort4 wpk[4];
      float ps = 0.f;
#pragma unroll
      for (int c = 0; c < 4; c++) {
        const float e0 = __expf(v[c][0] - mrow);
        const float e1 = __expf(v[c][1] - mrow);
        const float e2 = __expf(v[c][2] - mrow);
        const float e3 = __expf(v[c][3] - mrow);
        wpk[c].x = f2bf(e0); wpk[c].y = f2bf(e1);
        wpk[c].z = f2bf(e2); wpk[c].w = f2bf(e3);
        ps += (e0 + e1) + (e2 + e3);
      }
      lsum += ps;

      // ---- P -> per-wave feed tile (4 packed 8B writes) ----
#pragma unroll
      for (int c = 0; c < 4; c++)
        *(ushort4*)&Plf[plw0 + c * 256] = wpk[c];
      // wave-local data only: drain Plf writes; fence scheduler (rule 18)
      asm volatile("s_waitcnt lgkmcnt(0)" ::: "memory");
      __builtin_amdgcn_sched_barrier(0);

      // ---- O^T += V^T P over 64 kv (2 K=32 MFMAs per d0) ----
      const short8 pb0 = *(const short8*)&Plf[plrd];
      const short8 pb1 = *(const short8*)&Plf[plrd + 512];
      const int d7 = lr & 7;
      __builtin_amdgcn_s_setprio(1);
#pragma unroll
      for (int d0 = 0; d0 < 8; ++d0) {
        const int d = d0 * 16 + lr;
        const short8 vb0 = *(const short8*)&Vt[d * 64 + ((lg ^ d7) << 3)];
        o[d0] = __builtin_amdgcn_mfma_f32_16x16x32_bf16(vb0, pb0, o[d0], 0, 0, 0);
        const short8 vb1 = *(const short8*)&Vt[d * 64 + (((4 + lg) ^ d7) << 3)];
        o[d0] = __builtin_amdgcn_mfma_f32_16x16x32_bf16(vb1, pb1, o[d0], 0, 0, 0);
      }
      __builtin_amdgcn_s_setprio(0);
      __syncthreads();   // all Ks/Vt reads done before next staging
    }

    // ---- finalize lsum (lazy reduce) + store ctx ----
    float ls = lsum;
    ls += __shfl_xor(ls, 16);
    ls += __shfl_xor(ls, 32);
    const float inv = 1.0f / ls;
    unsigned short* crow = Ctx + base + (size_t)qrow * E_ + lg * 4;
#pragma unroll
    for (int d0 = 0; d0 < 8; ++d0) {
      ushort4 st;
      st.x = f2bf(o[d0][0] * inv);
      st.y = f2bf(o[d0][1] * inv);
      st.z = f2bf(o[d0][2] * inv);
      st.w = f2bf(o[d0][3] * inv);
      *(ushort4*)&crow[d0 * 16] = st;
    }
  }
}

// ---------------- launcher ----------------
extern "C" void kernel_launch(void* const* d_in, const int* in_sizes, int n_in,
                              void* d_out, int out_size, void* d_ws, size_t ws_size,
                              hipStream_t stream) {
  const float* x  = (const float*)d_in[0];
  // d_in[1] = causal_mask (tril) — implemented analytically
  const float* wq = (const float*)d_in[2];
  const float* bq = (const float*)d_in[3];
  const float* wk = (const float*)d_in[4];
  const float* bk = (const float*)d_in[5];
  const float* wv = (const float*)d_in[6];
  const float* bv = (const float*)d_in[7];
  const float* wo = (const float*)d_in[8];
  const float* bo = (const float*)d_in[9];
  float* out = (float*)d_out;

  char* ws = (char*)d_ws;
  const size_t MB = 1024 * 1024;
  unsigned short* xb  = (unsigned short*)(ws);             // 32 MB
  unsigned short* wqb = (unsigned short*)(ws + 32 * MB);   // 8 MB
  unsigned short* wkb = (unsigned short*)(ws + 40 * MB);   // 8 MB
  unsigned short* wvb = (unsigned short*)(ws + 48 * MB);   // 8 MB
  unsigned short* wob = (unsigned short*)(ws + 56 * MB);   // 8 MB
  unsigned short* Qb  = (unsigned short*)(ws + 64 * MB);   // 32 MB
  unsigned short* Kb  = (unsigned short*)(ws + 96 * MB);   // 32 MB
  unsigned short* VTb = (unsigned short*)(ws + 128 * MB);  // 32 MB, V^T [E][M]
  unsigned short* Cb  = (unsigned short*)(ws + 160 * MB);  // 32 MB -> 192 MB total

  const int nx4 = M_ * E_ / 4;   // x elements /4
  const int nw4 = E_ * E_ / 4;   // weight elements /4
  cast_bf16_kernel<<<nx4 / 256, 256, 0, stream>>>(x,  xb,  nx4);
  cast_bf16_kernel<<<nw4 / 256, 256, 0, stream>>>(wq, wqb, nw4);
  cast_bf16_kernel<<<nw4 / 256, 256, 0, stream>>>(wk, wkb, nw4);
  cast_bf16_kernel<<<nw4 / 256, 256, 0, stream>>>(wv, wvb, nw4);
  cast_bf16_kernel<<<nw4 / 256, 256, 0, stream>>>(wo, wob, nw4);

  const float scale = 0.08838834764831845f;  // 1/sqrt(128), folded into Q
  dim3 gg(E_ / 128, M_ / 128);   // (16, 64)
  gemm_bt<unsigned short><<<gg, 256, 0, stream>>>(xb, wqb, bq, Qb, M_, E_, E_, scale);
  gemm_bt<unsigned short><<<gg, 256, 0, stream>>>(xb, wkb, bk, Kb, M_, E_, E_, 1.0f);
  // V-projection writes V^T [E][M] directly (swapped-operand TR epilogue)
  gemm_bt<unsigned short, true><<<gg, 256, 0, stream>>>(xb, wvb, bv, VTb, M_, E_, E_, 1.0f);

  // folded causal grid: block bx handles q-tiles bx and 31-bx (33 x 64-kv steps)
  flash_attn<<<dim3(S_ / 64 / 2, H_, B_), 256, 0, stream>>>(Qb, Kb, VTb, Cb);

  gemm_bt<float><<<gg, 256, 0, stream>>>(Cb, wob, bo, out, M_, E_, E_, 1.0f);
}

// Round 11
// 565.501 us; speedup vs baseline: 1.2193x; 1.1496x over previous
//
#include <hip/hip_runtime.h>
#include <hip/hip_bf16.h>

// Problem constants
#define B_ 4
#define S_ 2048
#define E_ 2048
#define H_ 16
#define D_ 128
#define M_ (B_*S_)   // 8192 rows

typedef __attribute__((ext_vector_type(8))) short short8;
typedef __attribute__((ext_vector_type(4))) float f32x4;

__device__ __forceinline__ unsigned short f2bf(float f) {
  union { __hip_bfloat16 h; unsigned short u; } c;
  c.h = __float2bfloat16(f);
  return c.u;
}

__device__ __forceinline__ void gld_lds16(const void* g, void* l) {
  __builtin_amdgcn_global_load_lds((const __attribute__((address_space(1))) void*)g,
                                   (__attribute__((address_space(3))) void*)l, 16, 0, 0);
}

// ---------------- fp32 -> bf16 cast (vectorized) ----------------
__global__ __launch_bounds__(256) void cast_bf16_kernel(const float* __restrict__ in,
                                                        unsigned short* __restrict__ out,
                                                        int n4) {
  int i = blockIdx.x * 256 + threadIdx.x;
  if (i >= n4) return;
  float4 v = ((const float4*)in)[i];
  ushort4 o;
  o.x = f2bf(v.x); o.y = f2bf(v.y); o.z = f2bf(v.z); o.w = f2bf(v.w);
  ((ushort4*)out)[i] = o;
}

// ---------------- GEMM: C[M,N] = (A[M,K] @ W[N,K]^T + bias) * oscale ----------------
// m97 structure: 128x128 tile, BK=32, 4 waves (2x2 of 64x64), global_load_lds w16.
// TR=true: store C^T (C_T[N][M]) via swapped-operand MFMA (A-frag of X == B-frag
// of X^T, same lane regs): acc = mfma(bf, af) -> D[n][m], n = lg*4+r, m = lr.
// T1 XCD swizzle: chunked remap (bijective: nwg%8==0; all launches 1024 blocks)
// gives each XCD contiguous m-panels -> A/W panels stay in one L2.
template <typename OutT, bool TR = false>
__global__ __launch_bounds__(256) void gemm_bt(const unsigned short* __restrict__ A,
                                               const unsigned short* __restrict__ W,
                                               const float* __restrict__ bias,
                                               OutT* __restrict__ C,
                                               int M, int N, int K, float oscale) {
  __shared__ unsigned short As[128 * 32];
  __shared__ unsigned short Bs[128 * 32];
  const int tid  = threadIdx.x;
  const int lane = tid & 63;
  const int wid  = tid >> 6;
  // ---- XCD-aware chunked block swizzle (bijective: nwg % 8 == 0) ----
  const int nwg = gridDim.x * gridDim.y;
  const int lin = blockIdx.x + gridDim.x * blockIdx.y;
  const int nl  = (lin & 7) * (nwg >> 3) + (lin >> 3);
  const int m0 = (nl / gridDim.x) * 128;
  const int n0 = (nl % gridDim.x) * 128;
  const int wr = (wid >> 1) * 64;   // wave row offset in tile
  const int wc = (wid & 1) * 64;    // wave col offset in tile
  const int lr  = lane & 15;
  const int lk8 = (lane >> 4) * 8;

  f32x4 acc[4][4];
#pragma unroll
  for (int i = 0; i < 4; i++)
#pragma unroll
    for (int j = 0; j < 4; j++) acc[i][j] = (f32x4){0.f, 0.f, 0.f, 0.f};

  // staging: tile is 128 rows x 32 cols bf16 = 8192 B; 256 thr x 16 B = 4096 B/pass
  const int o0 = tid * 16;            // byte offset in tile, pass 0
  const int row0 = o0 >> 6, colb0 = o0 & 63;
  const int o1 = o0 + 4096;           // pass 1
  const int row1 = o1 >> 6, colb1 = o1 & 63;
  const int ldsb0 = wid * 1024;       // wave-uniform LDS byte base, pass 0
  const int ldsb1 = wid * 1024 + 4096;

  for (int kt = 0; kt < K; kt += 32) {
    gld_lds16(A + (size_t)(m0 + row0) * K + kt + (colb0 >> 1), (char*)As + ldsb0);
    gld_lds16(A + (size_t)(m0 + row1) * K + kt + (colb1 >> 1), (char*)As + ldsb1);
    gld_lds16(W + (size_t)(n0 + row0) * K + kt + (colb0 >> 1), (char*)Bs + ldsb0);
    gld_lds16(W + (size_t)(n0 + row1) * K + kt + (colb1 >> 1), (char*)Bs + ldsb1);
    __syncthreads();

    short8 af[4], bf[4];
#pragma unroll
    for (int i = 0; i < 4; i++) af[i] = *(const short8*)&As[(wr + i * 16 + lr) * 32 + lk8];
#pragma unroll
    for (int j = 0; j < 4; j++) bf[j] = *(const short8*)&Bs[(wc + j * 16 + lr) * 32 + lk8];
#pragma unroll
    for (int i = 0; i < 4; i++)
#pragma unroll
      for (int j = 0; j < 4; j++) {
        if constexpr (TR)
          acc[i][j] = __builtin_amdgcn_mfma_f32_16x16x32_bf16(bf[j], af[i], acc[i][j], 0, 0, 0);
        else
          acc[i][j] = __builtin_amdgcn_mfma_f32_16x16x32_bf16(af[i], bf[j], acc[i][j], 0, 0, 0);
      }
    __syncthreads();
  }

  if constexpr (TR) {
    // C^T epilogue: D[n][m], n = wc+j*16+lg*4+r, m = wr+i*16+lr  [swapped m89]
    const int lg4 = (lane >> 4) * 4;
#pragma unroll
    for (int j = 0; j < 4; j++) {
      const int gn = n0 + wc + j * 16 + lg4;
      const float4 bv4 = *(const float4*)&bias[gn];
#pragma unroll
      for (int i = 0; i < 4; i++) {
        const int gm = m0 + wr + i * 16 + lr;
#pragma unroll
        for (int r = 0; r < 4; r++) {
          const float v = (acc[i][j][r] + ((const float*)&bv4)[r]) * oscale;
          ((unsigned short*)C)[(size_t)(gn + r) * M + gm] = f2bf(v);
        }
      }
    }
  } else {
    // epilogue: C/D layout col=lane&15, row=(lane>>4)*4+r  [m89-verified]
#pragma unroll
    for (int i = 0; i < 4; i++) {
      const int gm = m0 + wr + i * 16 + (lane >> 4) * 4;
#pragma unroll
      for (int j = 0; j < 4; j++) {
        const int gn = n0 + wc + j * 16 + lr;
        const float bv = bias[gn];
#pragma unroll
        for (int r = 0; r < 4; r++) {
          const float v = (acc[i][j][r] + bv) * oscale;
          if constexpr (sizeof(OutT) == 2)
            ((unsigned short*)C)[(size_t)(gm + r) * N + gn] = f2bf(v);
          else
            ((float*)C)[(size_t)(gm + r) * N + gn] = v;
        }
      }
    }
  }
}

// ---------------- causal flash attention (folded, swapped ops, KVBLK=64) ----------------
// r9-verified structure: 4 waves/block, wave owns 16 q rows (64-row q-tile);
// block handles q-tiles bx and 31-bx -> 33 steps of 64 kv, balanced.
// Single-buffered; Q pre-scaled by 1/sqrt(D); masking only on diagonal step;
// lazy lsum; setprio around MFMA clusters.
//
// T1 XCD-aware block swizzle [r10 bug fixed]: grid is 1024 blocks (16x16x4).
//   nl = (lin&7)*128 + (lin>>3)   -- bijective on [0,1024) since 1024%8==0
// (r10 used *256 -> non-bijective, b decoded OOB; rule #11 exactly).
// Chunk c = lin&7 (~XCD id) gets nl in [c*128,(c+1)*128) = 8 complete
// (batch,head) groups of 16 blocks -> each head's K/V panels live in ONE L2.
__global__ __launch_bounds__(256, 4) void flash_attn(const unsigned short* __restrict__ Q,
                                                     const unsigned short* __restrict__ K,
                                                     const unsigned short* __restrict__ VT,
                                                     unsigned short* __restrict__ Ctx) {
  __shared__ unsigned short Ks[64 * 128];    // 16 KB, swizzled K tile
  __shared__ unsigned short Vt[128 * 64];    // 16 KB, swizzled V^T tile
  __shared__ unsigned short Pl[4 * 1024];    // 8 KB, per-wave P feed tiles

  const int tid  = threadIdx.x;
  const int lane = tid & 63;
  const int wid  = tid >> 6;
  const int lr  = lane & 15;
  const int lg  = lane >> 4;
  const int lk8 = lg * 8;
  // ---- XCD-aware chunked swizzle of (q-pair, head, batch); 1024 blocks ----
  const int lin = blockIdx.x + 16 * blockIdx.y + 256 * blockIdx.z;  // 0..1023
  const int nl  = (lin & 7) * 128 + (lin >> 3);                     // bijective
  const int bxw = nl & 15;           // q-pair tile index
  const int h   = (nl >> 4) & 15;    // head
  const int b   = nl >> 8;           // batch (0..3)
  const size_t base = ((size_t)b * S_) * E_ + (size_t)h * D_;
  const unsigned short* __restrict__ Kh = K + base;
  // VT head base: row h*D+d, col b*S+kv
  const unsigned short* __restrict__ VTh = VT + (size_t)(h * D_) * M_ + (size_t)b * S_;
  unsigned short* Plf = Pl + wid * 1024;

  // ---- K staging geometry: tile 64x128 = 16 KB; 4 passes x 4096 B ----
  const int rK = tid >> 4;                  // 0..15
  const int cK = ((tid * 16) & 255) ^ ((rK & 7) << 4);
  const unsigned short* ksrcB = Kh + (size_t)rK * E_ + (cK >> 1);
  char* kdstB = (char*)Ks + wid * 1024;     // + p*4096

  // ---- V^T staging geometry: tile 128 d x 128 B = 16 KB; 4 passes ----
  const int dVb = tid >> 3;                 // 0..31
  const int cV  = tid & 7;
  const unsigned short* vsrcB = VTh + (size_t)dVb * M_ + (size_t)((cV ^ (dVb & 7)) * 8);
  char* vdstB = (char*)Vt + wid * 1024;     // + p*4096

  // ---- P feed addresses (per-lane, constant across steps) ----
  const int plw0 = (lg >> 1) * 128 + lr * 8 + (lg & 1) * 4;  // pack c at +c*256
  const int plrd = lg * 128 + lr * 8;                         // B-frag kk at +kk*512

#pragma unroll 1
  for (int half = 0; half < 2; ++half) {
    const int ti = half ? (31 - bxw) : bxw;
    const int qblk = ti * 64;               // q-tile base
    const int q0w  = qblk + wid * 16;       // this wave's q rows
    const int qrow = q0w + lr;              // this lane's softmax row

    // ---- Q fragments (pre-scaled by 1/sqrt(D) in Q-GEMM) ----
    short8 qf[4];
#pragma unroll
    for (int kk = 0; kk < 4; kk++)
      qf[kk] = *(const short8*)&Q[base + (size_t)qrow * E_ + kk * 32 + lk8];

    f32x4 o[8];
#pragma unroll
    for (int d0 = 0; d0 < 8; d0++) o[d0] = (f32x4){0.f, 0.f, 0.f, 0.f};
    float mrow = -INFINITY;
    float lsum = 0.f;                       // per-lane partial (lazy reduce)

    const int nt = ti + 1;                  // steps of 64 kv

    for (int t = 0; t < nt; ++t) {
      const int kv0 = t * 64;
      const size_t koff = (size_t)kv0 * E_;

      // ---- stage K + V^T (8 async global_load_lds; zero staging VALU) ----
#pragma unroll
      for (int p = 0; p < 4; ++p) {
        gld_lds16(ksrcB + koff + (size_t)(16 * p) * E_, kdstB + p * 4096);
        gld_lds16(vsrcB + (size_t)(32 * p) * M_ + kv0,  vdstB + p * 4096);
      }
      __syncthreads();   // barrier drain: tile staged

      // ---- S^T = K Q^T : quadrant c holds S[kv0+c*16+lg*4+r][qrow] ----
      f32x4 s[4];
#pragma unroll
      for (int c = 0; c < 4; c++) s[c] = (f32x4){0.f, 0.f, 0.f, 0.f};
      const int swK = (lr & 7) << 4;
      __builtin_amdgcn_s_setprio(1);
#pragma unroll
      for (int kk = 0; kk < 4; kk++) {
        const int cb = (kk * 64 + lg * 16) ^ swK;
#pragma unroll
        for (int c = 0; c < 4; c++) {
          const short8 kf = *(const short8*)((const char*)Ks + (c * 16 + lr) * 256 + cb);
          s[c] = __builtin_amdgcn_mfma_f32_16x16x32_bf16(kf, qf[kk], s[c], 0, 0, 0);
        }
      }
      __builtin_amdgcn_s_setprio(0);

      // ---- scores (pre-scaled); mask only on the diagonal step ----
      float v[4][4];
#pragma unroll
      for (int c = 0; c < 4; c++)
#pragma unroll
        for (int r = 0; r < 4; r++) v[c][r] = s[c][r];
      if (t == nt - 1) {   // uniform branch: diagonal 64-block
#pragma unroll
        for (int c = 0; c < 4; c++) {
          const int kvq = kv0 + c * 16 + lg * 4;
#pragma unroll
          for (int r = 0; r < 4; r++)
            if (kvq + r > qrow) v[c][r] = -INFINITY;
        }
      }

      // ---- row max: 15 in-lane fmax + 2 shuffles ----
      float pm = fmaxf(fmaxf(fmaxf(v[0][0], v[0][1]), fmaxf(v[0][2], v[0][3])),
                       fmaxf(fmaxf(v[1][0], v[1][1]), fmaxf(v[1][2], v[1][3])));
      pm = fmaxf(pm, fmaxf(fmaxf(fmaxf(v[2][0], v[2][1]), fmaxf(v[2][2], v[2][3])),
                           fmaxf(fmaxf(v[3][0], v[3][1]), fmaxf(v[3][2], v[3][3]))));
      pm = fmaxf(pm, __shfl_xor(pm, 16));
      pm = fmaxf(pm, __shfl_xor(pm, 32));

      // ---- defer-max (T13, THR=8): rescale only when max grows a lot ----
      const float need = pm - mrow;          // first step: +inf -> slow path
      if (!__all(need <= 8.f)) {
        const float mnew = fmaxf(mrow, pm);
        const float al = __expf(mrow - mnew);   // first step: exp(-inf)=0
        lsum *= al;
#pragma unroll
        for (int d0 = 0; d0 < 8; ++d0) {
          f32x4 tt = o[d0];
          tt[0] *= al; tt[1] *= al; tt[2] *= al; tt[3] *= al;
          o[d0] = tt;
        }
        mrow = mnew;
      }

      // ---- exp + pack + per-lane partial sum (no per-step shuffles) ----
      ushort4 wpk[4];
      float ps = 0.f;
#pragma unroll
      for (int c = 0; c < 4; c++) {
        const float e0 = __expf(v[c][0] - mrow);
        const float e1 = __expf(v[c][1] - mrow);
        const float e2 = __expf(v[c][2] - mrow);
        const float e3 = __expf(v[c][3] - mrow);
        wpk[c].x = f2bf(e0); wpk[c].y = f2bf(e1);
        wpk[c].z = f2bf(e2); wpk[c].w = f2bf(e3);
        ps += (e0 + e1) + (e2 + e3);
      }
      lsum += ps;

      // ---- P -> per-wave feed tile (4 packed 8B writes) ----
#pragma unroll
      for (int c = 0; c < 4; c++)
        *(ushort4*)&Plf[plw0 + c * 256] = wpk[c];
      // wave-local data only: drain Plf writes; fence scheduler (rule 18)
      asm volatile("s_waitcnt lgkmcnt(0)" ::: "memory");
      __builtin_amdgcn_sched_barrier(0);

      // ---- O^T += V^T P over 64 kv (2 K=32 MFMAs per d0) ----
      const short8 pb0 = *(const short8*)&Plf[plrd];
      const short8 pb1 = *(const short8*)&Plf[plrd + 512];
      const int d7 = lr & 7;
      __builtin_amdgcn_s_setprio(1);
#pragma unroll
      for (int d0 = 0; d0 < 8; ++d0) {
        const int d = d0 * 16 + lr;
        const short8 vb0 = *(const short8*)&Vt[d * 64 + ((lg ^ d7) << 3)];
        o[d0] = __builtin_amdgcn_mfma_f32_16x16x32_bf16(vb0, pb0, o[d0], 0, 0, 0);
        const short8 vb1 = *(const short8*)&Vt[d * 64 + (((4 + lg) ^ d7) << 3)];
        o[d0] = __builtin_amdgcn_mfma_f32_16x16x32_bf16(vb1, pb1, o[d0], 0, 0, 0);
      }
      __builtin_amdgcn_s_setprio(0);
      __syncthreads();   // all Ks/Vt reads done before next staging
    }

    // ---- finalize lsum (lazy reduce) + store ctx ----
    float ls = lsum;
    ls += __shfl_xor(ls, 16);
    ls += __shfl_xor(ls, 32);
    const float inv = 1.0f / ls;
    unsigned short* crow = Ctx + base + (size_t)qrow * E_ + lg * 4;
#pragma unroll
    for (int d0 = 0; d0 < 8; ++d0) {
      ushort4 st;
      st.x = f2bf(o[d0][0] * inv);
      st.y = f2bf(o[d0][1] * inv);
      st.z = f2bf(o[d0][2] * inv);
      st.w = f2bf(o[d0][3] * inv);
      *(ushort4*)&crow[d0 * 16] = st;
    }
  }
}

// ---------------- launcher ----------------
extern "C" void kernel_launch(void* const* d_in, const int* in_sizes, int n_in,
                              void* d_out, int out_size, void* d_ws, size_t ws_size,
                              hipStream_t stream) {
  const float* x  = (const float*)d_in[0];
  // d_in[1] = causal_mask (tril) — implemented analytically
  const float* wq = (const float*)d_in[2];
  const float* bq = (const float*)d_in[3];
  const float* wk = (const float*)d_in[4];
  const float* bk = (const float*)d_in[5];
  const float* wv = (const float*)d_in[6];
  const float* bv = (const float*)d_in[7];
  const float* wo = (const float*)d_in[8];
  const float* bo = (const float*)d_in[9];
  float* out = (float*)d_out;

  char* ws = (char*)d_ws;
  const size_t MB = 1024 * 1024;
  unsigned short* xb  = (unsigned short*)(ws);             // 32 MB
  unsigned short* wqb = (unsigned short*)(ws + 32 * MB);   // 8 MB
  unsigned short* wkb = (unsigned short*)(ws + 40 * MB);   // 8 MB
  unsigned short* wvb = (unsigned short*)(ws + 48 * MB);   // 8 MB
  unsigned short* wob = (unsigned short*)(ws + 56 * MB);   // 8 MB
  unsigned short* Qb  = (unsigned short*)(ws + 64 * MB);   // 32 MB
  unsigned short* Kb  = (unsigned short*)(ws + 96 * MB);   // 32 MB
  unsigned short* VTb = (unsigned short*)(ws + 128 * MB);  // 32 MB, V^T [E][M]
  unsigned short* Cb  = (unsigned short*)(ws + 160 * MB);  // 32 MB -> 192 MB total

  const int nx4 = M_ * E_ / 4;   // x elements /4
  const int nw4 = E_ * E_ / 4;   // weight elements /4
  cast_bf16_kernel<<<nx4 / 256, 256, 0, stream>>>(x,  xb,  nx4);
  cast_bf16_kernel<<<nw4 / 256, 256, 0, stream>>>(wq, wqb, nw4);
  cast_bf16_kernel<<<nw4 / 256, 256, 0, stream>>>(wk, wkb, nw4);
  cast_bf16_kernel<<<nw4 / 256, 256, 0, stream>>>(wv, wvb, nw4);
  cast_bf16_kernel<<<nw4 / 256, 256, 0, stream>>>(wo, wob, nw4);

  const float scale = 0.08838834764831845f;  // 1/sqrt(128), folded into Q
  dim3 gg(E_ / 128, M_ / 128);   // (16, 64) -> 1024 blocks (%8 == 0)
  gemm_bt<unsigned short><<<gg, 256, 0, stream>>>(xb, wqb, bq, Qb, M_, E_, E_, scale);
  gemm_bt<unsigned short><<<gg, 256, 0, stream>>>(xb, wkb, bk, Kb, M_, E_, E_, 1.0f);
  // V-projection writes V^T [E][M] directly (swapped-operand TR epilogue)
  gemm_bt<unsigned short, true><<<gg, 256, 0, stream>>>(xb, wvb, bv, VTb, M_, E_, E_, 1.0f);

  // folded causal grid: block handles q-tiles bxw and 31-bxw (33 x 64-kv steps)
  flash_attn<<<dim3(S_ / 64 / 2, H_, B_), 256, 0, stream>>>(Qb, Kb, VTb, Cb);

  gemm_bt<float><<<gg, 256, 0, stream>>>(Cb, wob, bo, out, M_, E_, E_, 1.0f);
}

// Round 12
// 494.325 us; speedup vs baseline: 1.3949x; 1.1440x over previous
//
#include <hip/hip_runtime.h>
#include <hip/hip_bf16.h>

// Problem constants
#define B_ 4
#define S_ 2048
#define E_ 2048
#define H_ 16
#define D_ 128
#define M_ (B_*S_)   // 8192 rows

typedef __attribute__((ext_vector_type(8))) short short8;
typedef __attribute__((ext_vector_type(4))) float f32x4;

__device__ __forceinline__ unsigned short f2bf(float f) {
  union { __hip_bfloat16 h; unsigned short u; } c;
  c.h = __float2bfloat16(f);
  return c.u;
}

__device__ __forceinline__ void gld_lds16(const void* g, void* l) {
  __builtin_amdgcn_global_load_lds((const __attribute__((address_space(1))) void*)g,
                                   (__attribute__((address_space(3))) void*)l, 16, 0, 0);
}

// ---------------- fp32 -> bf16 cast (vectorized) ----------------
__global__ __launch_bounds__(256) void cast_bf16_kernel(const float* __restrict__ in,
                                                        unsigned short* __restrict__ out,
                                                        int n4) {
  int i = blockIdx.x * 256 + threadIdx.x;
  if (i >= n4) return;
  float4 v = ((const float4*)in)[i];
  ushort4 o;
  o.x = f2bf(v.x); o.y = f2bf(v.y); o.z = f2bf(v.z); o.w = f2bf(v.w);
  ((ushort4*)out)[i] = o;
}

// ---------------- GEMM: C[M,N] = (A[M,K] @ W[N,K]^T + bias) * oscale ----------------
// 128x128 tile, BK=64 (r12: halves barrier drains vs BK=32), 4 waves (2x2 of
// 64x64), global_load_lds w16 with XOR row-swizzle.
// LDS tiles [128][64] bf16 (128 B rows): raw reads would be 16-way bank
// conflicted; swizzle 16B-unit u ^= (row&7) applied on the GLOBAL source
// (linear LDS dest, rule 21) + same XOR on the read side -> 2-way (free).
// Staging pass p covers rows 32p..32p+31; 32p % 8 == 0 so each thread's
// swizzle constant is pass-invariant. Read row&7 == lr&7 (wr, i*16 % 8 == 0).
// TR=true: store C^T (C_T[N][M]) via swapped-operand MFMA (A-frag of X == B-frag
// of X^T, same lane regs): acc = mfma(bf, af) -> D[n][m], n = lg*4+r, m = lr.
// T1 XCD swizzle: chunked remap (bijective: nwg%8==0; all launches 1024 blocks).
template <typename OutT, bool TR = false>
__global__ __launch_bounds__(256) void gemm_bt(const unsigned short* __restrict__ A,
                                               const unsigned short* __restrict__ W,
                                               const float* __restrict__ bias,
                                               OutT* __restrict__ C,
                                               int M, int N, int K, float oscale) {
  __shared__ unsigned short As[128 * 64];   // 16 KB
  __shared__ unsigned short Bs[128 * 64];   // 16 KB
  const int tid  = threadIdx.x;
  const int lane = tid & 63;
  const int wid  = tid >> 6;
  // ---- XCD-aware chunked block swizzle (bijective: nwg % 8 == 0) ----
  const int nwg = gridDim.x * gridDim.y;
  const int lin = blockIdx.x + gridDim.x * blockIdx.y;
  const int nl  = (lin & 7) * (nwg >> 3) + (lin >> 3);
  const int m0 = (nl / gridDim.x) * 128;
  const int n0 = (nl % gridDim.x) * 128;
  const int wr = (wid >> 1) * 64;   // wave row offset in tile
  const int wc = (wid & 1) * 64;    // wave col offset in tile
  const int lr  = lane & 15;
  const int lg  = lane >> 4;

  f32x4 acc[4][4];
#pragma unroll
  for (int i = 0; i < 4; i++)
#pragma unroll
    for (int j = 0; j < 4; j++) acc[i][j] = (f32x4){0.f, 0.f, 0.f, 0.f};

  // ---- staging geometry: tile 128 rows x 128 B; 4 passes x 4096 B ----
  // pass p: row = (tid>>3) + 32p, 16B-unit = tid&7; global unit pre-swizzled.
  const int rS = tid >> 3;                  // 0..31
  const int uS = (tid & 7) ^ (rS & 7);      // pass-invariant swizzled unit
  const unsigned short* asrc = A + (size_t)(m0 + rS) * K + uS * 8;
  const unsigned short* bsrc = W + (size_t)(n0 + rS) * K + uS * 8;
  char* adst = (char*)As + wid * 1024;      // + p*4096 (lane*16 implicit)
  char* bdst = (char*)Bs + wid * 1024;

  const int swR = (lr & 7) << 4;            // read-side XOR (row&7 == lr&7)

  for (int kt = 0; kt < K; kt += 64) {
#pragma unroll
    for (int p = 0; p < 4; ++p) {
      gld_lds16(asrc + kt + (size_t)(32 * p) * K, adst + p * 4096);
      gld_lds16(bsrc + kt + (size_t)(32 * p) * K, bdst + p * 4096);
    }
    __syncthreads();

#pragma unroll
    for (int kk = 0; kk < 2; kk++) {
      const int cb = ((kk * 4 + lg) << 4) ^ swR;   // swizzled byte col
      short8 af[4], bf[4];
#pragma unroll
      for (int i = 0; i < 4; i++)
        af[i] = *(const short8*)((const char*)As + (wr + i * 16 + lr) * 128 + cb);
#pragma unroll
      for (int j = 0; j < 4; j++)
        bf[j] = *(const short8*)((const char*)Bs + (wc + j * 16 + lr) * 128 + cb);
#pragma unroll
      for (int i = 0; i < 4; i++)
#pragma unroll
        for (int j = 0; j < 4; j++) {
          if constexpr (TR)
            acc[i][j] = __builtin_amdgcn_mfma_f32_16x16x32_bf16(bf[j], af[i], acc[i][j], 0, 0, 0);
          else
            acc[i][j] = __builtin_amdgcn_mfma_f32_16x16x32_bf16(af[i], bf[j], acc[i][j], 0, 0, 0);
        }
    }
    __syncthreads();
  }

  if constexpr (TR) {
    // C^T epilogue: D[n][m], n = wc+j*16+lg*4+r, m = wr+i*16+lr  [swapped m89]
    const int lg4 = (lane >> 4) * 4;
#pragma unroll
    for (int j = 0; j < 4; j++) {
      const int gn = n0 + wc + j * 16 + lg4;
      const float4 bv4 = *(const float4*)&bias[gn];
#pragma unroll
      for (int i = 0; i < 4; i++) {
        const int gm = m0 + wr + i * 16 + lr;
#pragma unroll
        for (int r = 0; r < 4; r++) {
          const float v = (acc[i][j][r] + ((const float*)&bv4)[r]) * oscale;
          ((unsigned short*)C)[(size_t)(gn + r) * M + gm] = f2bf(v);
        }
      }
    }
  } else {
    // epilogue: C/D layout col=lane&15, row=(lane>>4)*4+r  [m89-verified]
#pragma unroll
    for (int i = 0; i < 4; i++) {
      const int gm = m0 + wr + i * 16 + (lane >> 4) * 4;
#pragma unroll
      for (int j = 0; j < 4; j++) {
        const int gn = n0 + wc + j * 16 + lr;
        const float bv = bias[gn];
#pragma unroll
        for (int r = 0; r < 4; r++) {
          const float v = (acc[i][j][r] + bv) * oscale;
          if constexpr (sizeof(OutT) == 2)
            ((unsigned short*)C)[(size_t)(gm + r) * N + gn] = f2bf(v);
          else
            ((float*)C)[(size_t)(gm + r) * N + gn] = v;
        }
      }
    }
  }
}

// ---------------- causal flash attention (folded, swapped ops, KVBLK=64) ----------------
// r11-verified, byte-identical. 4 waves/block, wave owns 16 q rows; block
// handles q-tiles bxw and 31-bxw -> 33 steps of 64 kv, balanced. Single-
// buffered; Q pre-scaled by 1/sqrt(D); masking only on diagonal step; lazy
// lsum; setprio around MFMA clusters; bijective XCD chunked swizzle.
__global__ __launch_bounds__(256, 4) void flash_attn(const unsigned short* __restrict__ Q,
                                                     const unsigned short* __restrict__ K,
                                                     const unsigned short* __restrict__ VT,
                                                     unsigned short* __restrict__ Ctx) {
  __shared__ unsigned short Ks[64 * 128];    // 16 KB, swizzled K tile
  __shared__ unsigned short Vt[128 * 64];    // 16 KB, swizzled V^T tile
  __shared__ unsigned short Pl[4 * 1024];    // 8 KB, per-wave P feed tiles

  const int tid  = threadIdx.x;
  const int lane = tid & 63;
  const int wid  = tid >> 6;
  const int lr  = lane & 15;
  const int lg  = lane >> 4;
  const int lk8 = lg * 8;
  // ---- XCD-aware chunked swizzle of (q-pair, head, batch); 1024 blocks ----
  const int lin = blockIdx.x + 16 * blockIdx.y + 256 * blockIdx.z;  // 0..1023
  const int nl  = (lin & 7) * 128 + (lin >> 3);                     // bijective
  const int bxw = nl & 15;           // q-pair tile index
  const int h   = (nl >> 4) & 15;    // head
  const int b   = nl >> 8;           // batch (0..3)
  const size_t base = ((size_t)b * S_) * E_ + (size_t)h * D_;
  const unsigned short* __restrict__ Kh = K + base;
  // VT head base: row h*D+d, col b*S+kv
  const unsigned short* __restrict__ VTh = VT + (size_t)(h * D_) * M_ + (size_t)b * S_;
  unsigned short* Plf = Pl + wid * 1024;

  // ---- K staging geometry: tile 64x128 = 16 KB; 4 passes x 4096 B ----
  const int rK = tid >> 4;                  // 0..15
  const int cK = ((tid * 16) & 255) ^ ((rK & 7) << 4);
  const unsigned short* ksrcB = Kh + (size_t)rK * E_ + (cK >> 1);
  char* kdstB = (char*)Ks + wid * 1024;     // + p*4096

  // ---- V^T staging geometry: tile 128 d x 128 B = 16 KB; 4 passes ----
  const int dVb = tid >> 3;                 // 0..31
  const int cV  = tid & 7;
  const unsigned short* vsrcB = VTh + (size_t)dVb * M_ + (size_t)((cV ^ (dVb & 7)) * 8);
  char* vdstB = (char*)Vt + wid * 1024;     // + p*4096

  // ---- P feed addresses (per-lane, constant across steps) ----
  const int plw0 = (lg >> 1) * 128 + lr * 8 + (lg & 1) * 4;  // pack c at +c*256
  const int plrd = lg * 128 + lr * 8;                         // B-frag kk at +kk*512

#pragma unroll 1
  for (int half = 0; half < 2; ++half) {
    const int ti = half ? (31 - bxw) : bxw;
    const int qblk = ti * 64;               // q-tile base
    const int q0w  = qblk + wid * 16;       // this wave's q rows
    const int qrow = q0w + lr;              // this lane's softmax row

    // ---- Q fragments (pre-scaled by 1/sqrt(D) in Q-GEMM) ----
    short8 qf[4];
#pragma unroll
    for (int kk = 0; kk < 4; kk++)
      qf[kk] = *(const short8*)&Q[base + (size_t)qrow * E_ + kk * 32 + lk8];

    f32x4 o[8];
#pragma unroll
    for (int d0 = 0; d0 < 8; d0++) o[d0] = (f32x4){0.f, 0.f, 0.f, 0.f};
    float mrow = -INFINITY;
    float lsum = 0.f;                       // per-lane partial (lazy reduce)

    const int nt = ti + 1;                  // steps of 64 kv

    for (int t = 0; t < nt; ++t) {
      const int kv0 = t * 64;
      const size_t koff = (size_t)kv0 * E_;

      // ---- stage K + V^T (8 async global_load_lds; zero staging VALU) ----
#pragma unroll
      for (int p = 0; p < 4; ++p) {
        gld_lds16(ksrcB + koff + (size_t)(16 * p) * E_, kdstB + p * 4096);
        gld_lds16(vsrcB + (size_t)(32 * p) * M_ + kv0,  vdstB + p * 4096);
      }
      __syncthreads();   // barrier drain: tile staged

      // ---- S^T = K Q^T : quadrant c holds S[kv0+c*16+lg*4+r][qrow] ----
      f32x4 s[4];
#pragma unroll
      for (int c = 0; c < 4; c++) s[c] = (f32x4){0.f, 0.f, 0.f, 0.f};
      const int swK = (lr & 7) << 4;
      __builtin_amdgcn_s_setprio(1);
#pragma unroll
      for (int kk = 0; kk < 4; kk++) {
        const int cb = (kk * 64 + lg * 16) ^ swK;
#pragma unroll
        for (int c = 0; c < 4; c++) {
          const short8 kf = *(const short8*)((const char*)Ks + (c * 16 + lr) * 256 + cb);
          s[c] = __builtin_amdgcn_mfma_f32_16x16x32_bf16(kf, qf[kk], s[c], 0, 0, 0);
        }
      }
      __builtin_amdgcn_s_setprio(0);

      // ---- scores (pre-scaled); mask only on the diagonal step ----
      float v[4][4];
#pragma unroll
      for (int c = 0; c < 4; c++)
#pragma unroll
        for (int r = 0; r < 4; r++) v[c][r] = s[c][r];
      if (t == nt - 1) {   // uniform branch: diagonal 64-block
#pragma unroll
        for (int c = 0; c < 4; c++) {
          const int kvq = kv0 + c * 16 + lg * 4;
#pragma unroll
          for (int r = 0; r < 4; r++)
            if (kvq + r > qrow) v[c][r] = -INFINITY;
        }
      }

      // ---- row max: 15 in-lane fmax + 2 shuffles ----
      float pm = fmaxf(fmaxf(fmaxf(v[0][0], v[0][1]), fmaxf(v[0][2], v[0][3])),
                       fmaxf(fmaxf(v[1][0], v[1][1]), fmaxf(v[1][2], v[1][3])));
      pm = fmaxf(pm, fmaxf(fmaxf(fmaxf(v[2][0], v[2][1]), fmaxf(v[2][2], v[2][3])),
                           fmaxf(fmaxf(v[3][0], v[3][1]), fmaxf(v[3][2], v[3][3]))));
      pm = fmaxf(pm, __shfl_xor(pm, 16));
      pm = fmaxf(pm, __shfl_xor(pm, 32));

      // ---- defer-max (T13, THR=8): rescale only when max grows a lot ----
      const float need = pm - mrow;          // first step: +inf -> slow path
      if (!__all(need <= 8.f)) {
        const float mnew = fmaxf(mrow, pm);
        const float al = __expf(mrow - mnew);   // first step: exp(-inf)=0
        lsum *= al;
#pragma unroll
        for (int d0 = 0; d0 < 8; ++d0) {
          f32x4 tt = o[d0];
          tt[0] *= al; tt[1] *= al; tt[2] *= al; tt[3] *= al;
          o[d0] = tt;
        }
        mrow = mnew;
      }

      // ---- exp + pack + per-lane partial sum (no per-step shuffles) ----
      ushort4 wpk[4];
      float ps = 0.f;
#pragma unroll
      for (int c = 0; c < 4; c++) {
        const float e0 = __expf(v[c][0] - mrow);
        const float e1 = __expf(v[c][1] - mrow);
        const float e2 = __expf(v[c][2] - mrow);
        const float e3 = __expf(v[c][3] - mrow);
        wpk[c].x = f2bf(e0); wpk[c].y = f2bf(e1);
        wpk[c].z = f2bf(e2); wpk[c].w = f2bf(e3);
        ps += (e0 + e1) + (e2 + e3);
      }
      lsum += ps;

      // ---- P -> per-wave feed tile (4 packed 8B writes) ----
#pragma unroll
      for (int c = 0; c < 4; c++)
        *(ushort4*)&Plf[plw0 + c * 256] = wpk[c];
      // wave-local data only: drain Plf writes; fence scheduler (rule 18)
      asm volatile("s_waitcnt lgkmcnt(0)" ::: "memory");
      __builtin_amdgcn_sched_barrier(0);

      // ---- O^T += V^T P over 64 kv (2 K=32 MFMAs per d0) ----
      const short8 pb0 = *(const short8*)&Plf[plrd];
      const short8 pb1 = *(const short8*)&Plf[plrd + 512];
      const int d7 = lr & 7;
      __builtin_amdgcn_s_setprio(1);
#pragma unroll
      for (int d0 = 0; d0 < 8; ++d0) {
        const int d = d0 * 16 + lr;
        const short8 vb0 = *(const short8*)&Vt[d * 64 + ((lg ^ d7) << 3)];
        o[d0] = __builtin_amdgcn_mfma_f32_16x16x32_bf16(vb0, pb0, o[d0], 0, 0, 0);
        const short8 vb1 = *(const short8*)&Vt[d * 64 + (((4 + lg) ^ d7) << 3)];
        o[d0] = __builtin_amdgcn_mfma_f32_16x16x32_bf16(vb1, pb1, o[d0], 0, 0, 0);
      }
      __builtin_amdgcn_s_setprio(0);
      __syncthreads();   // all Ks/Vt reads done before next staging
    }

    // ---- finalize lsum (lazy reduce) + store ctx ----
    float ls = lsum;
    ls += __shfl_xor(ls, 16);
    ls += __shfl_xor(ls, 32);
    const float inv = 1.0f / ls;
    unsigned short* crow = Ctx + base + (size_t)qrow * E_ + lg * 4;
#pragma unroll
    for (int d0 = 0; d0 < 8; ++d0) {
      ushort4 st;
      st.x = f2bf(o[d0][0] * inv);
      st.y = f2bf(o[d0][1] * inv);
      st.z = f2bf(o[d0][2] * inv);
      st.w = f2bf(o[d0][3] * inv);
      *(ushort4*)&crow[d0 * 16] = st;
    }
  }
}

// ---------------- launcher ----------------
extern "C" void kernel_launch(void* const* d_in, const int* in_sizes, int n_in,
                              void* d_out, int out_size, void* d_ws, size_t ws_size,
                              hipStream_t stream) {
  const float* x  = (const float*)d_in[0];
  // d_in[1] = causal_mask (tril) — implemented analytically
  const float* wq = (const float*)d_in[2];
  const float* bq = (const float*)d_in[3];
  const float* wk = (const float*)d_in[4];
  const float* bk = (const float*)d_in[5];
  const float* wv = (const float*)d_in[6];
  const float* bv = (const float*)d_in[7];
  const float* wo = (const float*)d_in[8];
  const float* bo = (const float*)d_in[9];
  float* out = (float*)d_out;

  char* ws = (char*)d_ws;
  const size_t MB = 1024 * 1024;
  unsigned short* xb  = (unsigned short*)(ws);             // 32 MB
  unsigned short* wqb = (unsigned short*)(ws + 32 * MB);   // 8 MB
  unsigned short* wkb = (unsigned short*)(ws + 40 * MB);   // 8 MB
  unsigned short* wvb = (unsigned short*)(ws + 48 * MB);   // 8 MB
  unsigned short* wob = (unsigned short*)(ws + 56 * MB);   // 8 MB
  unsigned short* Qb  = (unsigned short*)(ws + 64 * MB);   // 32 MB
  unsigned short* Kb  = (unsigned short*)(ws + 96 * MB);   // 32 MB
  unsigned short* VTb = (unsigned short*)(ws + 128 * MB);  // 32 MB, V^T [E][M]
  unsigned short* Cb  = (unsigned short*)(ws + 160 * MB);  // 32 MB -> 192 MB total

  const int nx4 = M_ * E_ / 4;   // x elements /4
  const int nw4 = E_ * E_ / 4;   // weight elements /4
  cast_bf16_kernel<<<nx4 / 256, 256, 0, stream>>>(x,  xb,  nx4);
  cast_bf16_kernel<<<nw4 / 256, 256, 0, stream>>>(wq, wqb, nw4);
  cast_bf16_kernel<<<nw4 / 256, 256, 0, stream>>>(wk, wkb, nw4);
  cast_bf16_kernel<<<nw4 / 256, 256, 0, stream>>>(wv, wvb, nw4);
  cast_bf16_kernel<<<nw4 / 256, 256, 0, stream>>>(wo, wob, nw4);

  const float scale = 0.08838834764831845f;  // 1/sqrt(128), folded into Q
  dim3 gg(E_ / 128, M_ / 128);   // (16, 64) -> 1024 blocks (%8 == 0)
  gemm_bt<unsigned short><<<gg, 256, 0, stream>>>(xb, wqb, bq, Qb, M_, E_, E_, scale);
  gemm_bt<unsigned short><<<gg, 256, 0, stream>>>(xb, wkb, bk, Kb, M_, E_, E_, 1.0f);
  // V-projection writes V^T [E][M] directly (swapped-operand TR epilogue)
  gemm_bt<unsigned short, true><<<gg, 256, 0, stream>>>(xb, wvb, bv, VTb, M_, E_, E_, 1.0f);

  // folded causal grid: block handles q-tiles bxw and 31-bxw (33 x 64-kv steps)
  flash_attn<<<dim3(S_ / 64 / 2, H_, B_), 256, 0, stream>>>(Qb, Kb, VTb, Cb);

  gemm_bt<float><<<gg, 256, 0, stream>>>(Cb, wob, bo, out, M_, E_, E_, 1.0f);
}

// Round 14
// 420.087 us; speedup vs baseline: 1.6414x; 1.1767x over previous
//
#include <hip/hip_runtime.h>
#include <hip/hip_bf16.h>

// Problem constants
#define B_ 4
#define S_ 2048
#define E_ 2048
#define H_ 16
#define D_ 128
#define M_ (B_*S_)   // 8192 rows

typedef __attribute__((ext_vector_type(8))) short short8;
typedef __attribute__((ext_vector_type(4))) float f32x4;

__device__ __forceinline__ unsigned short f2bf(float f) {
  union { __hip_bfloat16 h; unsigned short u; } c;
  c.h = __float2bfloat16(f);
  return c.u;
}

__device__ __forceinline__ void gld_lds16(const void* g, void* l) {
  __builtin_amdgcn_global_load_lds((const __attribute__((address_space(1))) void*)g,
                                   (__attribute__((address_space(3))) void*)l, 16, 0, 0);
}

// ---------------- fp32 -> bf16 cast (vectorized) ----------------
__global__ __launch_bounds__(256) void cast_bf16_kernel(const float* __restrict__ in,
                                                        unsigned short* __restrict__ out,
                                                        int n4) {
  int i = blockIdx.x * 256 + threadIdx.x;
  if (i >= n4) return;
  float4 v = ((const float4*)in)[i];
  ushort4 o;
  o.x = f2bf(v.x); o.y = f2bf(v.y); o.z = f2bf(v.z); o.w = f2bf(v.w);
  ((ushort4*)out)[i] = o;
}

// ---------------- GEMM 256x256: C[M,N] = (A[M,K] @ W[N,K]^T + bias) * oscale ----------------
// r14 = r13 with the dbuf stride bug fixed: one buffer = 256 rows x 128 B =
// 32768 B (r13 used 65536 -> buffer 1 aliased the other array; absmax 5e5).
// 256x256 tile, BK=64, 512 thr (8 waves, 2M x 4N), DOUBLE-BUFFERED LDS,
// ONE barrier per K-tile (T3-minimum):
//   prologue: stage tile0 -> buf0 (8 gld_lds)
//   iter t:   __syncthreads()          // vmcnt(0)+lgkm drain: buf[t&1] staged;
//                                      // all waves' reads of buf^1 finished
//             issue stage(t+1)->buf^1  // lands under the 64-MFMA compute
//             compute tile t from buf[t&1]
// Buffer safety: stage(t+1) targets buf^1, last READ in iter t-1; those
// ds_reads completed before iter t's top barrier (lgkm drain). Stage writes
// are vmcnt-tracked, drained at iter t+1's top barrier.
// LDS 128 KB -> 1 block/CU, 2 waves/SIMD; latency hiding via the pipeline.
// Byte audit: stage max = 32768 + 3*8192 + 8191 = 65535 < 65536 per array.
//
// LDS tiles [256][64] bf16, r12-verified XOR row-swizzle: 16B-unit
// u ^= (row&7) on the GLOBAL source (linear LDS dest, rule 21) + same XOR on
// reads -> 2-way (free). Staging issue i covers rows 64i..64i+63; 64i%8==0 so
// the per-thread swizzle constant is issue-invariant; read row&7 == lr&7.
// TR=true: store C^T via swapped-operand MFMA (m89-swapped epilogue).
// T1 XCD swizzle: chunked remap (bijective: nwg=256, %8==0).
template <typename OutT, bool TR = false>
__global__ __launch_bounds__(512) void gemm_bt256(const unsigned short* __restrict__ A,
                                                  const unsigned short* __restrict__ W,
                                                  const float* __restrict__ bias,
                                                  OutT* __restrict__ C,
                                                  int M, int N, int K, float oscale) {
  __shared__ unsigned short As[2 * 256 * 64];   // 2 x 32768 B
  __shared__ unsigned short Bs[2 * 256 * 64];   // 2 x 32768 B
  const int tid  = threadIdx.x;
  const int lane = tid & 63;
  const int wid  = tid >> 6;          // 0..7
  // ---- XCD-aware chunked block swizzle (bijective: nwg % 8 == 0) ----
  const int nwg = gridDim.x * gridDim.y;
  const int lin = blockIdx.x + gridDim.x * blockIdx.y;
  const int nl  = (lin & 7) * (nwg >> 3) + (lin >> 3);
  const int m0 = (nl / gridDim.x) * 256;
  const int n0 = (nl % gridDim.x) * 256;
  const int wr = (wid >> 2) * 128;    // wave row offset in tile (2 M-waves)
  const int wc = (wid & 3) * 64;      // wave col offset in tile (4 N-waves)
  const int lr  = lane & 15;
  const int lg  = lane >> 4;

  f32x4 acc[8][4];
#pragma unroll
  for (int i = 0; i < 8; i++)
#pragma unroll
    for (int j = 0; j < 4; j++) acc[i][j] = (f32x4){0.f, 0.f, 0.f, 0.f};

  // ---- staging geometry: per issue 512 thr x 16 B = 8 KB = 64 rows x 128 B ----
  // issue i: row = (tid>>3) + 64*i, 16B-unit = tid&7; global unit pre-swizzled.
  const int rS = tid >> 3;                  // 0..63
  const int uS = (tid & 7) ^ (rS & 7);      // issue-invariant swizzled unit
  const unsigned short* asrc = A + (size_t)(m0 + rS) * K + uS * 8;
  const unsigned short* bsrc = W + (size_t)(n0 + rS) * K + uS * 8;
  char* adst = (char*)As + wid * 1024;      // + buf*32768 + issue*8192
  char* bdst = (char*)Bs + wid * 1024;

  const int swR = (lr & 7) << 4;            // read-side XOR (row&7 == lr&7)
  const int nK = K >> 6;

  // ---- prologue: stage tile 0 into buf 0 ----
#pragma unroll
  for (int i = 0; i < 4; ++i) {
    gld_lds16(asrc + (size_t)(64 * i) * K, adst + i * 8192);
    gld_lds16(bsrc + (size_t)(64 * i) * K, bdst + i * 8192);
  }

  for (int t = 0; t < nK; ++t) {
    const int bo = (t & 1) * 32768;         // byte offset of current buffer
    __syncthreads();   // vmcnt+lgkm drain: buf staged; buf^1 reads all done

    // ---- issue next-tile staging into buf^1 (lands during compute) ----
    if (t + 1 < nK) {
      const int kt2 = (t + 1) * 64;
      const int nbo = bo ^ 32768;
#pragma unroll
      for (int i = 0; i < 4; ++i) {
        gld_lds16(asrc + kt2 + (size_t)(64 * i) * K, adst + nbo + i * 8192);
        gld_lds16(bsrc + kt2 + (size_t)(64 * i) * K, bdst + nbo + i * 8192);
      }
    }

    // ---- compute tile t: 2 k-slices x 2 m-halves x 16 MFMA ----
    const char* AsB = (const char*)As + bo;
    const char* BsB = (const char*)Bs + bo;
#pragma unroll
    for (int kk = 0; kk < 2; kk++) {
      const int cb = ((kk * 4 + lg) << 4) ^ swR;   // swizzled byte col
      short8 bf[4];
#pragma unroll
      for (int j = 0; j < 4; j++)
        bf[j] = *(const short8*)(BsB + (wc + j * 16 + lr) * 128 + cb);
#pragma unroll
      for (int mh = 0; mh < 2; mh++) {
        short8 af[4];
#pragma unroll
        for (int i = 0; i < 4; i++)
          af[i] = *(const short8*)(AsB + (wr + mh * 64 + i * 16 + lr) * 128 + cb);
        __builtin_amdgcn_s_setprio(1);
#pragma unroll
        for (int i = 0; i < 4; i++)
#pragma unroll
          for (int j = 0; j < 4; j++) {
            if constexpr (TR)
              acc[mh * 4 + i][j] = __builtin_amdgcn_mfma_f32_16x16x32_bf16(bf[j], af[i], acc[mh * 4 + i][j], 0, 0, 0);
            else
              acc[mh * 4 + i][j] = __builtin_amdgcn_mfma_f32_16x16x32_bf16(af[i], bf[j], acc[mh * 4 + i][j], 0, 0, 0);
          }
        __builtin_amdgcn_s_setprio(0);
      }
    }
  }

  if constexpr (TR) {
    // C^T epilogue: D[n][m], n = wc+j*16+lg*4+r, m = wr+i*16+lr  [swapped m89]
    const int lg4 = lg * 4;
#pragma unroll
    for (int j = 0; j < 4; j++) {
      const int gn = n0 + wc + j * 16 + lg4;
      const float4 bv4 = *(const float4*)&bias[gn];
#pragma unroll
      for (int i = 0; i < 8; i++) {
        const int gm = m0 + wr + i * 16 + lr;
#pragma unroll
        for (int r = 0; r < 4; r++) {
          const float v = (acc[i][j][r] + ((const float*)&bv4)[r]) * oscale;
          ((unsigned short*)C)[(size_t)(gn + r) * M + gm] = f2bf(v);
        }
      }
    }
  } else {
    // epilogue: C/D layout col=lane&15, row=(lane>>4)*4+r  [m89-verified]
#pragma unroll
    for (int i = 0; i < 8; i++) {
      const int gm = m0 + wr + i * 16 + lg * 4;
#pragma unroll
      for (int j = 0; j < 4; j++) {
        const int gn = n0 + wc + j * 16 + lr;
        const float bv = bias[gn];
#pragma unroll
        for (int r = 0; r < 4; r++) {
          const float v = (acc[i][j][r] + bv) * oscale;
          if constexpr (sizeof(OutT) == 2)
            ((unsigned short*)C)[(size_t)(gm + r) * N + gn] = f2bf(v);
          else
            ((float*)C)[(size_t)(gm + r) * N + gn] = v;
        }
      }
    }
  }
}

// ---------------- causal flash attention (folded, swapped ops, KVBLK=64) ----------------
// r11/r12-verified, byte-identical. 4 waves/block, wave owns 16 q rows; block
// handles q-tiles bxw and 31-bxw -> 33 steps of 64 kv, balanced. Single-
// buffered; Q pre-scaled by 1/sqrt(D); masking only on diagonal step; lazy
// lsum; setprio around MFMA clusters; bijective XCD chunked swizzle.
__global__ __launch_bounds__(256, 4) void flash_attn(const unsigned short* __restrict__ Q,
                                                     const unsigned short* __restrict__ K,
                                                     const unsigned short* __restrict__ VT,
                                                     unsigned short* __restrict__ Ctx) {
  __shared__ unsigned short Ks[64 * 128];    // 16 KB, swizzled K tile
  __shared__ unsigned short Vt[128 * 64];    // 16 KB, swizzled V^T tile
  __shared__ unsigned short Pl[4 * 1024];    // 8 KB, per-wave P feed tiles

  const int tid  = threadIdx.x;
  const int lane = tid & 63;
  const int wid  = tid >> 6;
  const int lr  = lane & 15;
  const int lg  = lane >> 4;
  const int lk8 = lg * 8;
  // ---- XCD-aware chunked swizzle of (q-pair, head, batch); 1024 blocks ----
  const int lin = blockIdx.x + 16 * blockIdx.y + 256 * blockIdx.z;  // 0..1023
  const int nl  = (lin & 7) * 128 + (lin >> 3);                     // bijective
  const int bxw = nl & 15;           // q-pair tile index
  const int h   = (nl >> 4) & 15;    // head
  const int b   = nl >> 8;           // batch (0..3)
  const size_t base = ((size_t)b * S_) * E_ + (size_t)h * D_;
  const unsigned short* __restrict__ Kh = K + base;
  // VT head base: row h*D+d, col b*S+kv
  const unsigned short* __restrict__ VTh = VT + (size_t)(h * D_) * M_ + (size_t)b * S_;
  unsigned short* Plf = Pl + wid * 1024;

  // ---- K staging geometry: tile 64x128 = 16 KB; 4 passes x 4096 B ----
  const int rK = tid >> 4;                  // 0..15
  const int cK = ((tid * 16) & 255) ^ ((rK & 7) << 4);
  const unsigned short* ksrcB = Kh + (size_t)rK * E_ + (cK >> 1);
  char* kdstB = (char*)Ks + wid * 1024;     // + p*4096

  // ---- V^T staging geometry: tile 128 d x 128 B = 16 KB; 4 passes ----
  const int dVb = tid >> 3;                 // 0..31
  const int cV  = tid & 7;
  const unsigned short* vsrcB = VTh + (size_t)dVb * M_ + (size_t)((cV ^ (dVb & 7)) * 8);
  char* vdstB = (char*)Vt + wid * 1024;     // + p*4096

  // ---- P feed addresses (per-lane, constant across steps) ----
  const int plw0 = (lg >> 1) * 128 + lr * 8 + (lg & 1) * 4;  // pack c at +c*256
  const int plrd = lg * 128 + lr * 8;                         // B-frag kk at +kk*512

#pragma unroll 1
  for (int half = 0; half < 2; ++half) {
    const int ti = half ? (31 - bxw) : bxw;
    const int qblk = ti * 64;               // q-tile base
    const int q0w  = qblk + wid * 16;       // this wave's q rows
    const int qrow = q0w + lr;              // this lane's softmax row

    // ---- Q fragments (pre-scaled by 1/sqrt(D) in Q-GEMM) ----
    short8 qf[4];
#pragma unroll
    for (int kk = 0; kk < 4; kk++)
      qf[kk] = *(const short8*)&Q[base + (size_t)qrow * E_ + kk * 32 + lk8];

    f32x4 o[8];
#pragma unroll
    for (int d0 = 0; d0 < 8; d0++) o[d0] = (f32x4){0.f, 0.f, 0.f, 0.f};
    float mrow = -INFINITY;
    float lsum = 0.f;                       // per-lane partial (lazy reduce)

    const int nt = ti + 1;                  // steps of 64 kv

    for (int t = 0; t < nt; ++t) {
      const int kv0 = t * 64;
      const size_t koff = (size_t)kv0 * E_;

      // ---- stage K + V^T (8 async global_load_lds; zero staging VALU) ----
#pragma unroll
      for (int p = 0; p < 4; ++p) {
        gld_lds16(ksrcB + koff + (size_t)(16 * p) * E_, kdstB + p * 4096);
        gld_lds16(vsrcB + (size_t)(32 * p) * M_ + kv0,  vdstB + p * 4096);
      }
      __syncthreads();   // barrier drain: tile staged

      // ---- S^T = K Q^T : quadrant c holds S[kv0+c*16+lg*4+r][qrow] ----
      f32x4 s[4];
#pragma unroll
      for (int c = 0; c < 4; c++) s[c] = (f32x4){0.f, 0.f, 0.f, 0.f};
      const int swK = (lr & 7) << 4;
      __builtin_amdgcn_s_setprio(1);
#pragma unroll
      for (int kk = 0; kk < 4; kk++) {
        const int cb = (kk * 64 + lg * 16) ^ swK;
#pragma unroll
        for (int c = 0; c < 4; c++) {
          const short8 kf = *(const short8*)((const char*)Ks + (c * 16 + lr) * 256 + cb);
          s[c] = __builtin_amdgcn_mfma_f32_16x16x32_bf16(kf, qf[kk], s[c], 0, 0, 0);
        }
      }
      __builtin_amdgcn_s_setprio(0);

      // ---- scores (pre-scaled); mask only on the diagonal step ----
      float v[4][4];
#pragma unroll
      for (int c = 0; c < 4; c++)
#pragma unroll
        for (int r = 0; r < 4; r++) v[c][r] = s[c][r];
      if (t == nt - 1) {   // uniform branch: diagonal 64-block
#pragma unroll
        for (int c = 0; c < 4; c++) {
          const int kvq = kv0 + c * 16 + lg * 4;
#pragma unroll
          for (int r = 0; r < 4; r++)
            if (kvq + r > qrow) v[c][r] = -INFINITY;
        }
      }

      // ---- row max: 15 in-lane fmax + 2 shuffles ----
      float pm = fmaxf(fmaxf(fmaxf(v[0][0], v[0][1]), fmaxf(v[0][2], v[0][3])),
                       fmaxf(fmaxf(v[1][0], v[1][1]), fmaxf(v[1][2], v[1][3])));
      pm = fmaxf(pm, fmaxf(fmaxf(fmaxf(v[2][0], v[2][1]), fmaxf(v[2][2], v[2][3])),
                           fmaxf(fmaxf(v[3][0], v[3][1]), fmaxf(v[3][2], v[3][3]))));
      pm = fmaxf(pm, __shfl_xor(pm, 16));
      pm = fmaxf(pm, __shfl_xor(pm, 32));

      // ---- defer-max (T13, THR=8): rescale only when max grows a lot ----
      const float need = pm - mrow;          // first step: +inf -> slow path
      if (!__all(need <= 8.f)) {
        const float mnew = fmaxf(mrow, pm);
        const float al = __expf(mrow - mnew);   // first step: exp(-inf)=0
        lsum *= al;
#pragma unroll
        for (int d0 = 0; d0 < 8; ++d0) {
          f32x4 tt = o[d0];
          tt[0] *= al; tt[1] *= al; tt[2] *= al; tt[3] *= al;
          o[d0] = tt;
        }
        mrow = mnew;
      }

      // ---- exp + pack + per-lane partial sum (no per-step shuffles) ----
      ushort4 wpk[4];
      float ps = 0.f;
#pragma unroll
      for (int c = 0; c < 4; c++) {
        const float e0 = __expf(v[c][0] - mrow);
        const float e1 = __expf(v[c][1] - mrow);
        const float e2 = __expf(v[c][2] - mrow);
        const float e3 = __expf(v[c][3] - mrow);
        wpk[c].x = f2bf(e0); wpk[c].y = f2bf(e1);
        wpk[c].z = f2bf(e2); wpk[c].w = f2bf(e3);
        ps += (e0 + e1) + (e2 + e3);
      }
      lsum += ps;

      // ---- P -> per-wave feed tile (4 packed 8B writes) ----
#pragma unroll
      for (int c = 0; c < 4; c++)
        *(ushort4*)&Plf[plw0 + c * 256] = wpk[c];
      // wave-local data only: drain Plf writes; fence scheduler (rule 18)
      asm volatile("s_waitcnt lgkmcnt(0)" ::: "memory");
      __builtin_amdgcn_sched_barrier(0);

      // ---- O^T += V^T P over 64 kv (2 K=32 MFMAs per d0) ----
      const short8 pb0 = *(const short8*)&Plf[plrd];
      const short8 pb1 = *(const short8*)&Plf[plrd + 512];
      const int d7 = lr & 7;
      __builtin_amdgcn_s_setprio(1);
#pragma unroll
      for (int d0 = 0; d0 < 8; ++d0) {
        const int d = d0 * 16 + lr;
        const short8 vb0 = *(const short8*)&Vt[d * 64 + ((lg ^ d7) << 3)];
        o[d0] = __builtin_amdgcn_mfma_f32_16x16x32_bf16(vb0, pb0, o[d0], 0, 0, 0);
        const short8 vb1 = *(const short8*)&Vt[d * 64 + (((4 + lg) ^ d7) << 3)];
        o[d0] = __builtin_amdgcn_mfma_f32_16x16x32_bf16(vb1, pb1, o[d0], 0, 0, 0);
      }
      __builtin_amdgcn_s_setprio(0);
      __syncthreads();   // all Ks/Vt reads done before next staging
    }

    // ---- finalize lsum (lazy reduce) + store ctx ----
    float ls = lsum;
    ls += __shfl_xor(ls, 16);
    ls += __shfl_xor(ls, 32);
    const float inv = 1.0f / ls;
    unsigned short* crow = Ctx + base + (size_t)qrow * E_ + lg * 4;
#pragma unroll
    for (int d0 = 0; d0 < 8; ++d0) {
      ushort4 st;
      st.x = f2bf(o[d0][0] * inv);
      st.y = f2bf(o[d0][1] * inv);
      st.z = f2bf(o[d0][2] * inv);
      st.w = f2bf(o[d0][3] * inv);
      *(ushort4*)&crow[d0 * 16] = st;
    }
  }
}

// ---------------- launcher ----------------
extern "C" void kernel_launch(void* const* d_in, const int* in_sizes, int n_in,
                              void* d_out, int out_size, void* d_ws, size_t ws_size,
                              hipStream_t stream) {
  const float* x  = (const float*)d_in[0];
  // d_in[1] = causal_mask (tril) — implemented analytically
  const float* wq = (const float*)d_in[2];
  const float* bq = (const float*)d_in[3];
  const float* wk = (const float*)d_in[4];
  const float* bk = (const float*)d_in[5];
  const float* wv = (const float*)d_in[6];
  const float* bv = (const float*)d_in[7];
  const float* wo = (const float*)d_in[8];
  const float* bo = (const float*)d_in[9];
  float* out = (float*)d_out;

  char* ws = (char*)d_ws;
  const size_t MB = 1024 * 1024;
  unsigned short* xb  = (unsigned short*)(ws);             // 32 MB
  unsigned short* wqb = (unsigned short*)(ws + 32 * MB);   // 8 MB
  unsigned short* wkb = (unsigned short*)(ws + 40 * MB);   // 8 MB
  unsigned short* wvb = (unsigned short*)(ws + 48 * MB);   // 8 MB
  unsigned short* wob = (unsigned short*)(ws + 56 * MB);   // 8 MB
  unsigned short* Qb  = (unsigned short*)(ws + 64 * MB);   // 32 MB
  unsigned short* Kb  = (unsigned short*)(ws + 96 * MB);   // 32 MB
  unsigned short* VTb = (unsigned short*)(ws + 128 * MB);  // 32 MB, V^T [E][M]
  unsigned short* Cb  = (unsigned short*)(ws + 160 * MB);  // 32 MB -> 192 MB total

  const int nx4 = M_ * E_ / 4;   // x elements /4
  const int nw4 = E_ * E_ / 4;   // weight elements /4
  cast_bf16_kernel<<<nx4 / 256, 256, 0, stream>>>(x,  xb,  nx4);
  cast_bf16_kernel<<<nw4 / 256, 256, 0, stream>>>(wq, wqb, nw4);
  cast_bf16_kernel<<<nw4 / 256, 256, 0, stream>>>(wk, wkb, nw4);
  cast_bf16_kernel<<<nw4 / 256, 256, 0, stream>>>(wv, wvb, nw4);
  cast_bf16_kernel<<<nw4 / 256, 256, 0, stream>>>(wo, wob, nw4);

  const float scale = 0.08838834764831845f;  // 1/sqrt(128), folded into Q
  dim3 gg(E_ / 256, M_ / 256);   // (8, 32) -> 256 blocks (%8 == 0)
  gemm_bt256<unsigned short><<<gg, 512, 0, stream>>>(xb, wqb, bq, Qb, M_, E_, E_, scale);
  gemm_bt256<unsigned short><<<gg, 512, 0, stream>>>(xb, wkb, bk, Kb, M_, E_, E_, 1.0f);
  // V-projection writes V^T [E][M] directly (swapped-operand TR epilogue)
  gemm_bt256<unsigned short, true><<<gg, 512, 0, stream>>>(xb, wvb, bv, VTb, M_, E_, E_, 1.0f);

  // folded causal grid: block handles q-tiles bxw and 31-bxw (33 x 64-kv steps)
  flash_attn<<<dim3(S_ / 64 / 2, H_, B_), 256, 0, stream>>>(Qb, Kb, VTb, Cb);

  gemm_bt256<float><<<gg, 512, 0, stream>>>(Cb, wob, bo, out, M_, E_, E_, 1.0f);
}